// Round 1
// baseline (3119.218 us; speedup 1.0000x reference)
//
#include <hip/hip_runtime.h>
#include <math.h>

// ---------------- problem constants ----------------
constexpr int NND = 4096;     // nodes
constexpr int EDG = 32768;    // edges
constexpr float SQRT3  = 1.7320508075688772f;
constexpr float ISQRT3 = 0.5773502691896258f;
constexpr float NORMI  = 1.0f / 32767.0f;   // 1/(E-1)

__device__ __forceinline__ float gelu_f(float x) {
    float x3 = x * x * x;
    return 0.5f * x * (1.0f + tanhf(0.7978845608028654f * (x + 0.044715f * x3)));
}
__device__ __forceinline__ float sigmoid_f(float x) {
    return 1.0f / (1.0f + expf(-x));
}

// acc[4*NO4] += x * w[0..4*NO4)
template<int NO4>
__device__ __forceinline__ void rank1(float* acc, float x, const float* w) {
#pragma unroll
    for (int u = 0; u < NO4; ++u) {
        const float4 q = *reinterpret_cast<const float4*>(w + 4 * u);
        acc[4*u+0] = fmaf(x, q.x, acc[4*u+0]);
        acc[4*u+1] = fmaf(x, q.y, acc[4*u+1]);
        acc[4*u+2] = fmaf(x, q.z, acc[4*u+2]);
        acc[4*u+3] = fmaf(x, q.w, acc[4*u+3]);
    }
}

// av[48] (16 outputs x 3 comps) += (t0,t1,t2) outer w[0..16)
__device__ __forceinline__ void rank1v(float* av, float t0, float t1, float t2, const float* wk) {
#pragma unroll
    for (int u = 0; u < 4; ++u) {
        const float4 q = *reinterpret_cast<const float4*>(wk + 4 * u);
        const float w0 = q.x, w1 = q.y, w2 = q.z, w3 = q.w;
        av[(4*u+0)*3+0] = fmaf(t0, w0, av[(4*u+0)*3+0]);
        av[(4*u+0)*3+1] = fmaf(t1, w0, av[(4*u+0)*3+1]);
        av[(4*u+0)*3+2] = fmaf(t2, w0, av[(4*u+0)*3+2]);
        av[(4*u+1)*3+0] = fmaf(t0, w1, av[(4*u+1)*3+0]);
        av[(4*u+1)*3+1] = fmaf(t1, w1, av[(4*u+1)*3+1]);
        av[(4*u+1)*3+2] = fmaf(t2, w1, av[(4*u+1)*3+2]);
        av[(4*u+2)*3+0] = fmaf(t0, w2, av[(4*u+2)*3+0]);
        av[(4*u+2)*3+1] = fmaf(t1, w2, av[(4*u+2)*3+1]);
        av[(4*u+2)*3+2] = fmaf(t2, w2, av[(4*u+2)*3+2]);
        av[(4*u+3)*3+0] = fmaf(t0, w3, av[(4*u+3)*3+0]);
        av[(4*u+3)*3+1] = fmaf(t1, w3, av[(4*u+3)*3+1]);
        av[(4*u+3)*3+2] = fmaf(t2, w3, av[(4*u+3)*3+2]);
    }
}

// ---------------- edge degree count ----------------
__global__ __launch_bounds__(256)
void segnn_cnt_kernel(const int* __restrict__ rcv, float* __restrict__ cnt) {
    const int e = blockIdx.x * 256 + threadIdx.x;
    if (e < EDG) atomicAdd(cnt + rcv[e], 1.0f);
}

// ---------------- edge block 0 ----------------
// 2 threads per edge: h in {0,1} owns scalar outputs [40h,40h+40) and vector outputs [8h,8h+8)
__global__ __launch_bounds__(128)
void segnn_eblk0_kernel(const float* __restrict__ cs, const float* __restrict__ cv,
                        const int* __restrict__ snd, const int* __restrict__ rcv,
                        const float* __restrict__ Ws, const float* __restrict__ Bs,
                        const float* __restrict__ Wv, float* __restrict__ msg) {
    const int t = blockIdx.x * 128 + threadIdx.x;
    const int e = t >> 1, h = t & 1;
    const int i = snd[e], j = rcv[e];
    const float* vi = cv + (size_t)i * 48;
    const float* vj = cv + (size_t)j * 48;
    const float rx = vi[0] - vj[0], ry = vi[1] - vj[1], rz = vi[2] - vj[2];
    const float rn = sqrtf(rx*rx + ry*ry + rz*rz);
    const float rinv = 1.0f / fmaxf(rn, 1e-9f);
    const float ux = rx*rinv, uy = ry*rinv, uz = rz*rinv;
    const int ob = 40*h, vb = 8*h;

    float acc[40], accu[8], accv[24];
#pragma unroll
    for (int u = 0; u < 40; ++u) acc[u] = Bs[ob + u];
#pragma unroll
    for (int u = 0; u < 8; ++u) accu[u] = 0.0f;
#pragma unroll
    for (int u = 0; u < 24; ++u) accv[u] = 0.0f;

    const float* sP[2] = { cs + (size_t)i * 64, cs + (size_t)j * 64 };
    const float* vP[2] = { vi, vj };
    // scalar rows 0..127:  x = sx[m]
    for (int part = 0; part < 2; ++part) {
        const float* sp  = sP[part];
        const float* wsr = Ws + (size_t)(part*64) * 80 + ob;
        const float* wvr = Wv + (size_t)(part*64) * 16 + vb;
#pragma unroll 2
        for (int m4 = 0; m4 < 16; ++m4) {
            const float4 xq = *reinterpret_cast<const float4*>(sp + 4*m4);
            const float xs_[4] = { xq.x, xq.y, xq.z, xq.w };
#pragma unroll
            for (int r = 0; r < 4; ++r) {
                const int m = 4*m4 + r;
                rank1<10>(acc,  xs_[r], wsr + m*80);
                rank1<2 >(accu, xs_[r], wvr + m*16);
            }
        }
    }
    // vector rows 128..159: dd x = vx.unit ; vs part for v-outputs
    for (int part = 0; part < 2; ++part) {
        const float* vp  = vP[part];
        const float* wsr = Ws + (size_t)(128 + part*16) * 80 + ob;
        const float* wvr = Wv + (size_t)(128 + part*16) * 16 + vb;
#pragma unroll 2
        for (int m = 0; m < 16; ++m) {
            const float a0 = vp[m*3+0], a1 = vp[m*3+1], a2 = vp[m*3+2];
            const float p = a0*ux + a1*uy + a2*uz;
            rank1<10>(acc, p, wsr + m*80);
            const float* wk = wvr + m*16;
#pragma unroll
            for (int oo = 0; oo < 8; ++oo) {
                const float wgt = wk[oo];
                accv[oo*3+0] = fmaf(a0, wgt, accv[oo*3+0]);
                accv[oo*3+1] = fmaf(a1, wgt, accv[oo*3+1]);
                accv[oo*3+2] = fmaf(a2, wgt, accv[oo*3+2]);
            }
        }
    }
    // gates: s[64..80) live in half1's acc[24..40)
    float g[8];
#pragma unroll
    for (int jj = 0; jj < 8; ++jj) {
        const float other = __shfl_xor(acc[24 + jj], 1);
        const float gv = (h == 0) ? other : acc[32 + jj];
        g[jj] = sigmoid_f(gv);
    }
    float* mrow = msg + (size_t)e * 116;
    const int ns = h ? 24 : 40;   // half1 only writes s[40..64)
    for (int u = 0; u < ns; ++u) mrow[ob + u] = gelu_f(acc[u]);
#pragma unroll
    for (int oo = 0; oo < 8; ++oo) {
        const float uo = accu[oo] * SQRT3;
        const float gg = g[oo];
        mrow[64 + (vb+oo)*3 + 0] = fmaf(uo, ux, accv[oo*3+0]) * gg;
        mrow[64 + (vb+oo)*3 + 1] = fmaf(uo, uy, accv[oo*3+1]) * gg;
        mrow[64 + (vb+oo)*3 + 2] = fmaf(uo, uz, accv[oo*3+2]) * gg;
    }
    if (h == 0) { mrow[112] = ux; mrow[113] = uy; mrow[114] = uz; }
}

// ---------------- edge blocks 1,2 (E2=80). ATOMIC=1: aggregate instead of write ----------------
template<int ATOMIC>
__global__ __launch_bounds__(128)
void segnn_eblk12_kernel(float* __restrict__ msg, const int* __restrict__ rcv,
                         const float* __restrict__ Ws, const float* __restrict__ Bs,
                         const float* __restrict__ Wv,
                         float* __restrict__ sum_s, float* __restrict__ sum_v,
                         float* __restrict__ sum_u) {
    const int t = blockIdx.x * 128 + threadIdx.x;
    const int e = t >> 1, h = t & 1;
    float* mrow = msg + (size_t)e * 116;
    const float ux = mrow[112], uy = mrow[113], uz = mrow[114];
    const int ob = 40*h, vb = 8*h;

    float acc[40], accu[8], accv[24];
#pragma unroll
    for (int u = 0; u < 40; ++u) acc[u] = Bs[ob + u];
#pragma unroll
    for (int u = 0; u < 8; ++u) accu[u] = 0.0f;
#pragma unroll
    for (int u = 0; u < 24; ++u) accv[u] = 0.0f;

    const float* wsr = Ws + ob;
    const float* wvr = Wv + vb;
#pragma unroll 2
    for (int m4 = 0; m4 < 16; ++m4) {
        const float4 xq = *reinterpret_cast<const float4*>(mrow + 4*m4);
        const float xs_[4] = { xq.x, xq.y, xq.z, xq.w };
#pragma unroll
        for (int r = 0; r < 4; ++r) {
            const int m = 4*m4 + r;
            rank1<10>(acc,  xs_[r], wsr + m*80);
            rank1<2 >(accu, xs_[r], wvr + m*16);
        }
    }
#pragma unroll 2
    for (int m = 0; m < 16; ++m) {
        const float a0 = mrow[64+m*3+0], a1 = mrow[64+m*3+1], a2 = mrow[64+m*3+2];
        const float p = a0*ux + a1*uy + a2*uz;
        rank1<10>(acc, p, wsr + (64+m)*80);
        const float* wk = wvr + (64+m)*16;
#pragma unroll
        for (int oo = 0; oo < 8; ++oo) {
            const float wgt = wk[oo];
            accv[oo*3+0] = fmaf(a0, wgt, accv[oo*3+0]);
            accv[oo*3+1] = fmaf(a1, wgt, accv[oo*3+1]);
            accv[oo*3+2] = fmaf(a2, wgt, accv[oo*3+2]);
        }
    }
    float g[8];
#pragma unroll
    for (int jj = 0; jj < 8; ++jj) {
        const float other = __shfl_xor(acc[24 + jj], 1);
        const float gv = (h == 0) ? other : acc[32 + jj];
        g[jj] = sigmoid_f(gv);
    }
    const int ns = h ? 24 : 40;
    if (ATOMIC) {
        const int j = rcv[e];
        float* ss = sum_s + (size_t)j * 64;
        for (int u = 0; u < ns; ++u) atomicAdd(ss + ob + u, gelu_f(acc[u]));
        float* sv = sum_v + (size_t)j * 48;
#pragma unroll
        for (int oo = 0; oo < 8; ++oo) {
            const float uo = accu[oo] * SQRT3;
            const float gg = g[oo];
            atomicAdd(sv + (vb+oo)*3 + 0, fmaf(uo, ux, accv[oo*3+0]) * gg);
            atomicAdd(sv + (vb+oo)*3 + 1, fmaf(uo, uy, accv[oo*3+1]) * gg);
            atomicAdd(sv + (vb+oo)*3 + 2, fmaf(uo, uz, accv[oo*3+2]) * gg);
        }
        if (h == 0) {
            atomicAdd(sum_u + (size_t)j*3 + 0, ux);
            atomicAdd(sum_u + (size_t)j*3 + 1, uy);
            atomicAdd(sum_u + (size_t)j*3 + 2, uz);
        }
    } else {
        for (int u = 0; u < ns; ++u) mrow[ob + u] = gelu_f(acc[u]);
#pragma unroll
        for (int oo = 0; oo < 8; ++oo) {
            const float uo = accu[oo] * SQRT3;
            const float gg = g[oo];
            mrow[64 + (vb+oo)*3 + 0] = fmaf(uo, ux, accv[oo*3+0]) * gg;
            mrow[64 + (vb+oo)*3 + 1] = fmaf(uo, uy, accv[oo*3+1]) * gg;
            mrow[64 + (vb+oo)*3 + 2] = fmaf(uo, uz, accv[oo*3+2]) * gg;
        }
    }
}

// ---------------- build y from sums (and zero sums for next step) ----------------
__global__ __launch_bounds__(128)
void segnn_y_kernel(float* __restrict__ sum_s, float* __restrict__ sum_v,
                    float* __restrict__ sum_u, const float* __restrict__ cnt,
                    float* __restrict__ y_s, float* __restrict__ y_v) {
    const int n = blockIdx.x;
    const int f = threadIdx.x;
    if (f >= 116) return;
    const float c  = cnt[n];
    const float cc = fmaxf(c, 1.0f);
    const float inv = 1.0f / cc * NORMI;
    if (f < 64) {
        y_s[(size_t)n*65 + f] = sum_s[(size_t)n*64 + f] * inv;
        sum_s[(size_t)n*64 + f] = 0.0f;
    } else if (f == 64) {
        y_s[(size_t)n*65 + 64] = (c > 0.5f) ? NORMI : 0.0f;
    } else if (f < 113) {
        const int k = f - 65;
        y_v[(size_t)n*51 + k] = sum_v[(size_t)n*48 + k] * inv;
        sum_v[(size_t)n*48 + k] = 0.0f;
    } else {
        const int d = f - 113;
        y_v[(size_t)n*51 + 48 + d] = SQRT3 * sum_u[(size_t)n*3 + d] * inv;
        sum_u[(size_t)n*3 + d] = 0.0f;
    }
}

// ---------------- node TP-gate block ----------------
// 512 threads: 16 nodes x 32 K-slices. X generated on the fly from LDS.
__global__ __launch_bounds__(512, 2)
void segnn_node_kernel(const float* __restrict__ in_s, const float* __restrict__ in_v,
                       const float* __restrict__ y_s, const float* __restrict__ y_v,
                       const float* __restrict__ W,  const float* __restrict__ B,
                       const float* __restrict__ Wv,
                       float* __restrict__ out_s, float* __restrict__ out_v) {
    __shared__ float xs[16][65];
    __shared__ float xv[16][49];
    __shared__ float ysL[16][65];
    __shared__ float yvL[16][53];
    __shared__ float red[8][16][49];
    __shared__ float fin_s[16][81];
    __shared__ float fin_v[16][49];

    const int tid = threadIdx.x;
    const int nb0 = blockIdx.x * 16;
    for (int idx = tid; idx < 16*64; idx += 512) { const int n = idx >> 6, m = idx & 63; xs[n][m] = in_s[(size_t)(nb0+n)*64 + m]; }
    for (int idx = tid; idx < 16*48; idx += 512) { const int n = idx / 48, m = idx - n*48; xv[n][m] = in_v[(size_t)(nb0+n)*48 + m]; }
    for (int idx = tid; idx < 16*65; idx += 512) { const int n = idx / 65, m = idx - n*65; ysL[n][m] = y_s[(size_t)(nb0+n)*65 + m]; }
    for (int idx = tid; idx < 16*51; idx += 512) { const int n = idx / 51, m = idx - n*51; yvL[n][m] = y_v[(size_t)(nb0+n)*51 + m]; }
    __syncthreads();

    const int n = tid & 15, slice = tid >> 4;      // slice 0..31
    const int lane = tid & 63, wv = tid >> 6;      // wave 0..7
    const int dm  = slice >> 1;                    // dd: m per slice-pair, k halves
    const int dk0 = (slice & 1) ? 9 : 0,  dk1 = (slice & 1) ? 17 : 9;
    const int vm  = slice >> 1;                    // vs: m per slice-pair, k halves
    const int vk0 = (slice & 1) ? 33 : 0, vk1 = (slice & 1) ? 65 : 33;

    // ---- scalar output: two passes of 40 columns ----
#pragma unroll 1
    for (int pass = 0; pass < 2; ++pass) {
        const int ob = 40 * pass;
        float acc[40];
#pragma unroll
        for (int u = 0; u < 40; ++u) acc[u] = 0.0f;
        // ss rows: m in {2*slice, 2*slice+1}, all k<65
#pragma unroll 1
        for (int mi = 0; mi < 2; ++mi) {
            const int m = 2*slice + mi;
            const float xm = xs[n][m];
            const float* wr = W + (size_t)(m*65) * 80 + ob;
#pragma unroll 2
            for (int k = 0; k < 65; ++k) {
                const float x = xm * ysL[n][k];
                rank1<10>(acc, x, wr + k*80);
            }
        }
        // dd rows
        {
            const float v0 = xv[n][dm*3+0], v1 = xv[n][dm*3+1], v2 = xv[n][dm*3+2];
            const float* wr = W + (size_t)(4160 + dm*17) * 80 + ob;
#pragma unroll 2
            for (int k = dk0; k < dk1; ++k) {
                const float x = (v0*yvL[n][k*3+0] + v1*yvL[n][k*3+1] + v2*yvL[n][k*3+2]) * ISQRT3;
                rank1<10>(acc, x, wr + k*80);
            }
        }
        // reduce 4 slices within wave
#pragma unroll
        for (int u = 0; u < 40; ++u) {
            acc[u] += __shfl_xor(acc[u], 16);
            acc[u] += __shfl_xor(acc[u], 32);
        }
        if (lane < 16) {
#pragma unroll
            for (int u = 0; u < 40; ++u) red[wv][lane][u] = acc[u];
        }
        __syncthreads();
        for (int idx = tid; idx < 16*40; idx += 512) {
            const int nn = idx / 40, oo = idx - nn*40;
            float s = 0.0f;
#pragma unroll
            for (int ww = 0; ww < 8; ++ww) s += red[ww][nn][oo];
            fin_s[nn][ob + oo] = s + B[ob + oo];
        }
        __syncthreads();
    }

    // ---- vector output: 16 outputs x 3 comps ----
    {
        float av[48];
#pragma unroll
        for (int u = 0; u < 48; ++u) av[u] = 0.0f;
        // sv rows: m in {2*slice, 2*slice+1}, k<17;  X = s[m]*yv[k,:]
#pragma unroll 1
        for (int mi = 0; mi < 2; ++mi) {
            const int m = 2*slice + mi;
            const float xm = xs[n][m];
            const float* wr = Wv + (size_t)(m*17) * 16;
#pragma unroll 2
            for (int k = 0; k < 17; ++k) {
                rank1v(av, xm*yvL[n][k*3+0], xm*yvL[n][k*3+1], xm*yvL[n][k*3+2], wr + k*16);
            }
        }
        // vs rows: m = vm, k half;  X = v[m,:]*ys[k]
        {
            const float b0 = xv[n][vm*3+0], b1 = xv[n][vm*3+1], b2 = xv[n][vm*3+2];
            const float* wr = Wv + (size_t)(1088 + vm*65) * 16;
#pragma unroll 2
            for (int k = vk0; k < vk1; ++k) {
                const float yk = ysL[n][k];
                rank1v(av, b0*yk, b1*yk, b2*yk, wr + k*16);
            }
        }
#pragma unroll
        for (int u = 0; u < 48; ++u) {
            av[u] += __shfl_xor(av[u], 16);
            av[u] += __shfl_xor(av[u], 32);
        }
        if (lane < 16) {
#pragma unroll
            for (int u = 0; u < 48; ++u) red[wv][lane][u] = av[u];
        }
        __syncthreads();
        for (int idx = tid; idx < 16*48; idx += 512) {
            const int nn = idx / 48, oo = idx - nn*48;
            float s = 0.0f;
#pragma unroll
            for (int ww = 0; ww < 8; ++ww) s += red[ww][nn][oo];
            fin_v[nn][oo] = s;
        }
        __syncthreads();
    }

    // ---- epilogue: gelu / sigmoid-gate, write ----
    for (int idx = tid; idx < 16*112; idx += 512) {
        const int nn = idx / 112, f = idx - nn*112;
        if (f < 64) {
            out_s[(size_t)(nb0+nn)*64 + f] = gelu_f(fin_s[nn][f]);
        } else {
            const int r = f - 64;
            const int o = r / 3;
            const float gg = sigmoid_f(fin_s[nn][64 + o]);
            out_v[(size_t)(nb0+nn)*48 + r] = fin_v[nn][r] * gg;
        }
    }
}

// ---------------- per-step final Linear ----------------
__global__ __launch_bounds__(256)
void segnn_linear_kernel(const float* __restrict__ in_s, const float* __restrict__ in_v,
                         const float* __restrict__ lws, const float* __restrict__ lb,
                         const float* __restrict__ lwv,
                         float* __restrict__ out_s, float* __restrict__ out_v,
                         float* __restrict__ out_cat) {
    const int idx = blockIdx.x * 256 + threadIdx.x;
    if (idx >= NND * 112) return;
    const int nidx = idx / 112, f = idx - nidx * 112;
    if (f < 48) {
        const int k = f / 3, d = f - 3*k;
        const float* vp = in_v + (size_t)nidx * 48 + d;
        float acc = 0.0f;
#pragma unroll
        for (int m = 0; m < 16; ++m) acc = fmaf(vp[m*3], lwv[m*16 + k], acc);
        if (out_cat) out_cat[(size_t)nidx*112 + f] = acc;
        else         out_v[(size_t)nidx*48 + f] = acc;
    } else {
        const int o = f - 48;
        const float* sp = in_s + (size_t)nidx * 64;
        float acc = lb[o];
#pragma unroll
        for (int m = 0; m < 64; ++m) acc = fmaf(sp[m], lws[m*64 + o], acc);
        if (out_cat) out_cat[(size_t)nidx*112 + f] = acc;
        else         out_s[(size_t)nidx*64 + o] = acc;
    }
}

// ---------------- host launcher ----------------
extern "C" void kernel_launch(void* const* d_in, const int* in_sizes, int n_in,
                              void* d_out, int out_size, void* d_ws, size_t ws_size,
                              hipStream_t stream) {
    const float* in_s  = (const float*)d_in[0];
    const float* in_v  = (const float*)d_in[1];
    const int*   snd   = (const int*)  d_in[2];
    const int*   rcv   = (const int*)  d_in[3];
    const float* e1_ws = (const float*)d_in[4];
    const float* e1_b  = (const float*)d_in[5];
    const float* e1_wv = (const float*)d_in[6];
    const float* e2_ws = (const float*)d_in[7];
    const float* e2_b  = (const float*)d_in[8];
    const float* e2_wv = (const float*)d_in[9];
    const float* n_ws  = (const float*)d_in[10];
    const float* n_b   = (const float*)d_in[11];
    const float* n_wv  = (const float*)d_in[12];
    const float* l_ws  = (const float*)d_in[13];
    const float* l_b   = (const float*)d_in[14];
    const float* l_wv  = (const float*)d_in[15];

    float* ws    = (float*)d_ws;
    float* cur_s = ws;                           // N*64
    float* cur_v = cur_s + 262144;               // N*48
    float* nxt_s = cur_v + 196608;               // N*64
    float* nxt_v = nxt_s + 262144;               // N*48
    float* msg   = nxt_v + 196608;               // E*116
    float* sum_s = msg + (size_t)EDG * 116;      // N*64
    float* sum_v = sum_s + 262144;               // N*48
    float* sum_u = sum_v + 196608;               // N*3
    float* cnt   = sum_u + 12288;                // N
    float* y_s   = cnt + 4096;                   // N*65
    float* y_v   = y_s + 266240;                 // N*51

    // zero accumulators (sum_s, sum_v, sum_u, cnt are contiguous)
    hipMemsetAsync(sum_s, 0, (size_t)(262144 + 196608 + 12288 + 4096) * sizeof(float), stream);
    hipMemcpyAsync(cur_s, in_s, (size_t)262144 * sizeof(float), hipMemcpyDeviceToDevice, stream);
    hipMemcpyAsync(cur_v, in_v, (size_t)196608 * sizeof(float), hipMemcpyDeviceToDevice, stream);
    segnn_cnt_kernel<<<EDG/256, 256, 0, stream>>>(rcv, cnt);

    for (int step = 0; step < 3; ++step) {
        segnn_eblk0_kernel<<<512, 128, 0, stream>>>(cur_s, cur_v, snd, rcv,
            e1_ws + (size_t)step*160*80, e1_b + step*80, e1_wv + (size_t)step*160*16, msg);
        segnn_eblk12_kernel<0><<<512, 128, 0, stream>>>(msg, rcv,
            e2_ws + (size_t)(step*2+0)*80*80, e2_b + (step*2+0)*80, e2_wv + (size_t)(step*2+0)*80*16,
            nullptr, nullptr, nullptr);
        segnn_eblk12_kernel<1><<<512, 128, 0, stream>>>(msg, rcv,
            e2_ws + (size_t)(step*2+1)*80*80, e2_b + (step*2+1)*80, e2_wv + (size_t)(step*2+1)*80*16,
            sum_s, sum_v, sum_u);
        segnn_y_kernel<<<NND, 128, 0, stream>>>(sum_s, sum_v, sum_u, cnt, y_s, y_v);

        segnn_node_kernel<<<NND/16, 512, 0, stream>>>(cur_s, cur_v, y_s, y_v,
            n_ws + (size_t)(step*3+0)*4432*80, n_b + (step*3+0)*80, n_wv + (size_t)(step*3+0)*2128*16,
            nxt_s, nxt_v);
        segnn_node_kernel<<<NND/16, 512, 0, stream>>>(nxt_s, nxt_v, y_s, y_v,
            n_ws + (size_t)(step*3+1)*4432*80, n_b + (step*3+1)*80, n_wv + (size_t)(step*3+1)*2128*16,
            cur_s, cur_v);
        segnn_node_kernel<<<NND/16, 512, 0, stream>>>(cur_s, cur_v, y_s, y_v,
            n_ws + (size_t)(step*3+2)*4432*80, n_b + (step*3+2)*80, n_wv + (size_t)(step*3+2)*2128*16,
            nxt_s, nxt_v);

        segnn_linear_kernel<<<(NND*112 + 255)/256, 256, 0, stream>>>(nxt_s, nxt_v,
            l_ws + (size_t)step*64*64, l_b + step*64, l_wv + (size_t)step*16*16,
            cur_s, cur_v, (step == 2) ? (float*)d_out : nullptr);
    }
}

// Round 2
// 2553.036 us; speedup vs baseline: 1.2218x; 1.2218x over previous
//
#include <hip/hip_runtime.h>
#include <math.h>

// ---------------- problem constants ----------------
constexpr int NND = 4096;     // nodes
constexpr int EDG = 32768;    // edges
constexpr float SQRT3  = 1.7320508075688772f;
constexpr float ISQRT3 = 0.5773502691896258f;
constexpr float NORMI  = 1.0f / 32767.0f;   // 1/(E-1)

__device__ __forceinline__ float gelu_f(float x) {
    float x3 = x * x * x;
    return 0.5f * x * (1.0f + tanhf(0.7978845608028654f * (x + 0.044715f * x3)));
}
__device__ __forceinline__ float sigmoid_f(float x) {
    return 1.0f / (1.0f + expf(-x));
}

// acc[4*NO4] += x * w[0..4*NO4)
template<int NO4>
__device__ __forceinline__ void rank1(float* acc, float x, const float* w) {
#pragma unroll
    for (int u = 0; u < NO4; ++u) {
        const float4 q = *reinterpret_cast<const float4*>(w + 4 * u);
        acc[4*u+0] = fmaf(x, q.x, acc[4*u+0]);
        acc[4*u+1] = fmaf(x, q.y, acc[4*u+1]);
        acc[4*u+2] = fmaf(x, q.z, acc[4*u+2]);
        acc[4*u+3] = fmaf(x, q.w, acc[4*u+3]);
    }
}

// av[48] (16 outputs x 3 comps) += (t0,t1,t2) outer w[0..16)
__device__ __forceinline__ void rank1v(float* av, float t0, float t1, float t2, const float* wk) {
#pragma unroll
    for (int u = 0; u < 4; ++u) {
        const float4 q = *reinterpret_cast<const float4*>(wk + 4 * u);
        const float w0 = q.x, w1 = q.y, w2 = q.z, w3 = q.w;
        av[(4*u+0)*3+0] = fmaf(t0, w0, av[(4*u+0)*3+0]);
        av[(4*u+0)*3+1] = fmaf(t1, w0, av[(4*u+0)*3+1]);
        av[(4*u+0)*3+2] = fmaf(t2, w0, av[(4*u+0)*3+2]);
        av[(4*u+1)*3+0] = fmaf(t0, w1, av[(4*u+1)*3+0]);
        av[(4*u+1)*3+1] = fmaf(t1, w1, av[(4*u+1)*3+1]);
        av[(4*u+1)*3+2] = fmaf(t2, w1, av[(4*u+1)*3+2]);
        av[(4*u+2)*3+0] = fmaf(t0, w2, av[(4*u+2)*3+0]);
        av[(4*u+2)*3+1] = fmaf(t1, w2, av[(4*u+2)*3+1]);
        av[(4*u+2)*3+2] = fmaf(t2, w2, av[(4*u+2)*3+2]);
        av[(4*u+3)*3+0] = fmaf(t0, w3, av[(4*u+3)*3+0]);
        av[(4*u+3)*3+1] = fmaf(t1, w3, av[(4*u+3)*3+1]);
        av[(4*u+3)*3+2] = fmaf(t2, w3, av[(4*u+3)*3+2]);
    }
}

// ---------------- edge degree count ----------------
__global__ __launch_bounds__(256)
void segnn_cnt_kernel(const int* __restrict__ rcv, float* __restrict__ cnt) {
    const int e = blockIdx.x * 256 + threadIdx.x;
    if (e < EDG) atomicAdd(cnt + rcv[e], 1.0f);
}

// ---------------- fused edge pipeline (blocks 0,1,2 + aggregation) ----------------
// 256 threads = 64 edges x 4 threads/edge. Thread h owns scalar cols [20h,20h+20)
// and vector cols [4h,4h+4). Intermediates live in LDS, never hit global.
template<int NSX, int NVX>
__device__ __forceinline__ void edge_phase(int e, int h, float ux, float uy, float uz,
                                           const float XS[64][129], const float XV[64][97],
                                           const float* __restrict__ Ws,
                                           const float* __restrict__ B,
                                           const float* __restrict__ Wv,
                                           float* acc, float* accu, float* accv) {
#pragma unroll
    for (int u = 0; u < 20; ++u) acc[u] = B[20*h + u];
#pragma unroll
    for (int u = 0; u < 4; ++u) accu[u] = 0.0f;
#pragma unroll
    for (int u = 0; u < 12; ++u) accv[u] = 0.0f;
    const float* wsr = Ws + 20*h;
    const float* wvr = Wv + 4*h;
#pragma unroll 4
    for (int m = 0; m < NSX; ++m) {
        const float x = XS[e][m];
        rank1<5>(acc,  x, wsr + (size_t)m*80);
        rank1<1>(accu, x, wvr + (size_t)m*16);
    }
#pragma unroll 2
    for (int m = 0; m < NVX; ++m) {
        const float a0 = XV[e][3*m+0], a1 = XV[e][3*m+1], a2 = XV[e][3*m+2];
        const float p = a0*ux + a1*uy + a2*uz;
        rank1<5>(acc, p, wsr + (size_t)(NSX+m)*80);
        const float4 wq = *reinterpret_cast<const float4*>(wvr + (size_t)(NSX+m)*16);
        const float wk[4] = { wq.x, wq.y, wq.z, wq.w };
#pragma unroll
        for (int oo = 0; oo < 4; ++oo) {
            accv[oo*3+0] = fmaf(a0, wk[oo], accv[oo*3+0]);
            accv[oo*3+1] = fmaf(a1, wk[oo], accv[oo*3+1]);
            accv[oo*3+2] = fmaf(a2, wk[oo], accv[oo*3+2]);
        }
    }
}

__global__ __launch_bounds__(256, 2)
void segnn_edge_fused(const float* __restrict__ cs, const float* __restrict__ cv,
                      const int* __restrict__ snd, const int* __restrict__ rcv,
                      const float* __restrict__ W0s, const float* __restrict__ B0, const float* __restrict__ W0v,
                      const float* __restrict__ W1s, const float* __restrict__ B1, const float* __restrict__ W1v,
                      const float* __restrict__ W2s, const float* __restrict__ B2, const float* __restrict__ W2v,
                      float* __restrict__ sum_s, float* __restrict__ sum_v, float* __restrict__ sum_u) {
    __shared__ float XS[64][129];   // scalar x (phase0: 128 = s_i|s_j; later: 64)
    __shared__ float XV[64][97];    // vector x (phase0: 96 = v_i|v_j; later: 48)
    __shared__ float UU[64][4];     // unit vector per edge
    __shared__ float GG[64][16];    // raw gate pre-activations (h=3 -> all)

    const int tid = threadIdx.x;
    const int e0  = blockIdx.x * 64;

    for (int idx = tid; idx < 64*128; idx += 256) {
        const int e = idx >> 7, m = idx & 127;
        const int node = (m < 64) ? snd[e0+e] : rcv[e0+e];
        XS[e][m] = cs[(size_t)node*64 + (m & 63)];
    }
    for (int idx = tid; idx < 64*96; idx += 256) {
        const int e = idx / 96, m = idx - e*96;
        const int node = (m < 48) ? snd[e0+e] : rcv[e0+e];
        XV[e][m] = cv[(size_t)node*48 + (m < 48 ? m : m - 48)];
    }
    __syncthreads();
    if (tid < 64) {
        const float rx = XV[tid][0]-XV[tid][48], ry = XV[tid][1]-XV[tid][49], rz = XV[tid][2]-XV[tid][50];
        const float rinv = 1.0f / fmaxf(sqrtf(rx*rx+ry*ry+rz*rz), 1e-9f);
        UU[tid][0] = rx*rinv; UU[tid][1] = ry*rinv; UU[tid][2] = rz*rinv;
    }
    __syncthreads();

    const int e = tid >> 2, h = tid & 3;
    const float ux = UU[e][0], uy = UU[e][1], uz = UU[e][2];
    float acc[20], accu[4], accv[12];

    // ---- phase 0 (E1 = 160 rows) ----
    edge_phase<128,32>(e, h, ux, uy, uz, XS, XV, W0s, B0, W0v, acc, accu, accv);
    __syncthreads();                           // all reads of XS/XV done
    if (h == 3) {
#pragma unroll
        for (int u = 0; u < 16; ++u) GG[e][u] = acc[4+u];
    }
    {
        const int ns = (h == 3) ? 4 : 20;
        for (int u = 0; u < ns; ++u) XS[e][20*h + u] = gelu_f(acc[u]);
    }
    __syncthreads();                           // gates + scalars visible
#pragma unroll
    for (int oo = 0; oo < 4; ++oo) {
        const float g  = sigmoid_f(GG[e][4*h + oo]);
        const float uo = accu[oo] * SQRT3;
        XV[e][(4*h+oo)*3+0] = fmaf(uo, ux, accv[oo*3+0]) * g;
        XV[e][(4*h+oo)*3+1] = fmaf(uo, uy, accv[oo*3+1]) * g;
        XV[e][(4*h+oo)*3+2] = fmaf(uo, uz, accv[oo*3+2]) * g;
    }
    __syncthreads();

    // ---- phase 1 (E2 = 80 rows) ----
    edge_phase<64,16>(e, h, ux, uy, uz, XS, XV, W1s, B1, W1v, acc, accu, accv);
    __syncthreads();
    if (h == 3) {
#pragma unroll
        for (int u = 0; u < 16; ++u) GG[e][u] = acc[4+u];
    }
    {
        const int ns = (h == 3) ? 4 : 20;
        for (int u = 0; u < ns; ++u) XS[e][20*h + u] = gelu_f(acc[u]);
    }
    __syncthreads();
#pragma unroll
    for (int oo = 0; oo < 4; ++oo) {
        const float g  = sigmoid_f(GG[e][4*h + oo]);
        const float uo = accu[oo] * SQRT3;
        XV[e][(4*h+oo)*3+0] = fmaf(uo, ux, accv[oo*3+0]) * g;
        XV[e][(4*h+oo)*3+1] = fmaf(uo, uy, accv[oo*3+1]) * g;
        XV[e][(4*h+oo)*3+2] = fmaf(uo, uz, accv[oo*3+2]) * g;
    }
    __syncthreads();

    // ---- phase 2 (E2 = 80 rows) + aggregation ----
    edge_phase<64,16>(e, h, ux, uy, uz, XS, XV, W2s, B2, W2v, acc, accu, accv);
    __syncthreads();
    if (h == 3) {
#pragma unroll
        for (int u = 0; u < 16; ++u) GG[e][u] = acc[4+u];
    }
    __syncthreads();
    {
        const int j = rcv[e0 + e];
        float* ss = sum_s + (size_t)j * 64;
        const int ns = (h == 3) ? 4 : 20;
        for (int u = 0; u < ns; ++u) atomicAdd(ss + 20*h + u, gelu_f(acc[u]));
        float* sv = sum_v + (size_t)j * 48;
#pragma unroll
        for (int oo = 0; oo < 4; ++oo) {
            const float g  = sigmoid_f(GG[e][4*h + oo]);
            const float uo = accu[oo] * SQRT3;
            atomicAdd(sv + (4*h+oo)*3 + 0, fmaf(uo, ux, accv[oo*3+0]) * g);
            atomicAdd(sv + (4*h+oo)*3 + 1, fmaf(uo, uy, accv[oo*3+1]) * g);
            atomicAdd(sv + (4*h+oo)*3 + 2, fmaf(uo, uz, accv[oo*3+2]) * g);
        }
        if (h == 0) {
            atomicAdd(sum_u + (size_t)j*3 + 0, ux);
            atomicAdd(sum_u + (size_t)j*3 + 1, uy);
            atomicAdd(sum_u + (size_t)j*3 + 2, uz);
        }
    }
}

// ---------------- build y from sums (and zero sums for next step) ----------------
__global__ __launch_bounds__(128)
void segnn_y_kernel(float* __restrict__ sum_s, float* __restrict__ sum_v,
                    float* __restrict__ sum_u, const float* __restrict__ cnt,
                    float* __restrict__ y_s, float* __restrict__ y_v) {
    const int n = blockIdx.x;
    const int f = threadIdx.x;
    if (f >= 116) return;
    const float c  = cnt[n];
    const float cc = fmaxf(c, 1.0f);
    const float inv = 1.0f / cc * NORMI;
    if (f < 64) {
        y_s[(size_t)n*65 + f] = sum_s[(size_t)n*64 + f] * inv;
        sum_s[(size_t)n*64 + f] = 0.0f;
    } else if (f == 64) {
        y_s[(size_t)n*65 + 64] = (c > 0.5f) ? NORMI : 0.0f;
    } else if (f < 113) {
        const int k = f - 65;
        y_v[(size_t)n*51 + k] = sum_v[(size_t)n*48 + k] * inv;
        sum_v[(size_t)n*48 + k] = 0.0f;
    } else {
        const int d = f - 113;
        y_v[(size_t)n*51 + 48 + d] = SQRT3 * sum_u[(size_t)n*3 + d] * inv;
        sum_u[(size_t)n*3 + d] = 0.0f;
    }
}

// ---------------- node TP-gate block ----------------
// 512 threads: 16 nodes x 32 K-slices. X generated on the fly from LDS.
__global__ __launch_bounds__(512, 2)
void segnn_node_kernel(const float* __restrict__ in_s, const float* __restrict__ in_v,
                       const float* __restrict__ y_s, const float* __restrict__ y_v,
                       const float* __restrict__ W,  const float* __restrict__ B,
                       const float* __restrict__ Wv,
                       float* __restrict__ out_s, float* __restrict__ out_v) {
    __shared__ float xs[16][65];
    __shared__ float xv[16][49];
    __shared__ float ysL[16][65];
    __shared__ float yvL[16][53];
    __shared__ float red[8][16][49];
    __shared__ float fin_s[16][81];
    __shared__ float fin_v[16][49];

    const int tid = threadIdx.x;
    const int nb0 = blockIdx.x * 16;
    for (int idx = tid; idx < 16*64; idx += 512) { const int n = idx >> 6, m = idx & 63; xs[n][m] = in_s[(size_t)(nb0+n)*64 + m]; }
    for (int idx = tid; idx < 16*48; idx += 512) { const int n = idx / 48, m = idx - n*48; xv[n][m] = in_v[(size_t)(nb0+n)*48 + m]; }
    for (int idx = tid; idx < 16*65; idx += 512) { const int n = idx / 65, m = idx - n*65; ysL[n][m] = y_s[(size_t)(nb0+n)*65 + m]; }
    for (int idx = tid; idx < 16*51; idx += 512) { const int n = idx / 51, m = idx - n*51; yvL[n][m] = y_v[(size_t)(nb0+n)*51 + m]; }
    __syncthreads();

    const int n = tid & 15, slice = tid >> 4;      // slice 0..31
    const int lane = tid & 63, wv = tid >> 6;      // wave 0..7
    const int dm  = slice >> 1;                    // dd: m per slice-pair, k halves
    const int dk0 = (slice & 1) ? 9 : 0,  dk1 = (slice & 1) ? 17 : 9;
    const int vm  = slice >> 1;                    // vs: m per slice-pair, k halves
    const int vk0 = (slice & 1) ? 33 : 0, vk1 = (slice & 1) ? 65 : 33;

    // ---- scalar output: two passes of 40 columns ----
#pragma unroll 1
    for (int pass = 0; pass < 2; ++pass) {
        const int ob = 40 * pass;
        float acc[40];
#pragma unroll
        for (int u = 0; u < 40; ++u) acc[u] = 0.0f;
        // ss rows: m in {2*slice, 2*slice+1}, all k<65
#pragma unroll 1
        for (int mi = 0; mi < 2; ++mi) {
            const int m = 2*slice + mi;
            const float xm = xs[n][m];
            const float* wr = W + (size_t)(m*65) * 80 + ob;
#pragma unroll 2
            for (int k = 0; k < 65; ++k) {
                const float x = xm * ysL[n][k];
                rank1<10>(acc, x, wr + k*80);
            }
        }
        // dd rows
        {
            const float v0 = xv[n][dm*3+0], v1 = xv[n][dm*3+1], v2 = xv[n][dm*3+2];
            const float* wr = W + (size_t)(4160 + dm*17) * 80 + ob;
#pragma unroll 2
            for (int k = dk0; k < dk1; ++k) {
                const float x = (v0*yvL[n][k*3+0] + v1*yvL[n][k*3+1] + v2*yvL[n][k*3+2]) * ISQRT3;
                rank1<10>(acc, x, wr + k*80);
            }
        }
        // reduce 4 slices within wave
#pragma unroll
        for (int u = 0; u < 40; ++u) {
            acc[u] += __shfl_xor(acc[u], 16);
            acc[u] += __shfl_xor(acc[u], 32);
        }
        if (lane < 16) {
#pragma unroll
            for (int u = 0; u < 40; ++u) red[wv][lane][u] = acc[u];
        }
        __syncthreads();
        for (int idx = tid; idx < 16*40; idx += 512) {
            const int nn = idx / 40, oo = idx - nn*40;
            float s = 0.0f;
#pragma unroll
            for (int ww = 0; ww < 8; ++ww) s += red[ww][nn][oo];
            fin_s[nn][ob + oo] = s + B[ob + oo];
        }
        __syncthreads();
    }

    // ---- vector output: 16 outputs x 3 comps ----
    {
        float av[48];
#pragma unroll
        for (int u = 0; u < 48; ++u) av[u] = 0.0f;
        // sv rows: m in {2*slice, 2*slice+1}, k<17;  X = s[m]*yv[k,:]
#pragma unroll 1
        for (int mi = 0; mi < 2; ++mi) {
            const int m = 2*slice + mi;
            const float xm = xs[n][m];
            const float* wr = Wv + (size_t)(m*17) * 16;
#pragma unroll 2
            for (int k = 0; k < 17; ++k) {
                rank1v(av, xm*yvL[n][k*3+0], xm*yvL[n][k*3+1], xm*yvL[n][k*3+2], wr + k*16);
            }
        }
        // vs rows: m = vm, k half;  X = v[m,:]*ys[k]
        {
            const float b0 = xv[n][vm*3+0], b1 = xv[n][vm*3+1], b2 = xv[n][vm*3+2];
            const float* wr = Wv + (size_t)(1088 + vm*65) * 16;
#pragma unroll 2
            for (int k = vk0; k < vk1; ++k) {
                const float yk = ysL[n][k];
                rank1v(av, b0*yk, b1*yk, b2*yk, wr + k*16);
            }
        }
#pragma unroll
        for (int u = 0; u < 48; ++u) {
            av[u] += __shfl_xor(av[u], 16);
            av[u] += __shfl_xor(av[u], 32);
        }
        if (lane < 16) {
#pragma unroll
            for (int u = 0; u < 48; ++u) red[wv][lane][u] = av[u];
        }
        __syncthreads();
        for (int idx = tid; idx < 16*48; idx += 512) {
            const int nn = idx / 48, oo = idx - nn*48;
            float s = 0.0f;
#pragma unroll
            for (int ww = 0; ww < 8; ++ww) s += red[ww][nn][oo];
            fin_v[nn][oo] = s;
        }
        __syncthreads();
    }

    // ---- epilogue: gelu / sigmoid-gate, write ----
    for (int idx = tid; idx < 16*112; idx += 512) {
        const int nn = idx / 112, f = idx - nn*112;
        if (f < 64) {
            out_s[(size_t)(nb0+nn)*64 + f] = gelu_f(fin_s[nn][f]);
        } else {
            const int r = f - 64;
            const int o = r / 3;
            const float gg = sigmoid_f(fin_s[nn][64 + o]);
            out_v[(size_t)(nb0+nn)*48 + r] = fin_v[nn][r] * gg;
        }
    }
}

// ---------------- per-step final Linear ----------------
__global__ __launch_bounds__(256)
void segnn_linear_kernel(const float* __restrict__ in_s, const float* __restrict__ in_v,
                         const float* __restrict__ lws, const float* __restrict__ lb,
                         const float* __restrict__ lwv,
                         float* __restrict__ out_s, float* __restrict__ out_v,
                         float* __restrict__ out_cat) {
    const int idx = blockIdx.x * 256 + threadIdx.x;
    if (idx >= NND * 112) return;
    const int nidx = idx / 112, f = idx - nidx * 112;
    if (f < 48) {
        const int k = f / 3, d = f - 3*k;
        const float* vp = in_v + (size_t)nidx * 48 + d;
        float acc = 0.0f;
#pragma unroll
        for (int m = 0; m < 16; ++m) acc = fmaf(vp[m*3], lwv[m*16 + k], acc);
        if (out_cat) out_cat[(size_t)nidx*112 + f] = acc;
        else         out_v[(size_t)nidx*48 + f] = acc;
    } else {
        const int o = f - 48;
        const float* sp = in_s + (size_t)nidx * 64;
        float acc = lb[o];
#pragma unroll
        for (int m = 0; m < 64; ++m) acc = fmaf(sp[m], lws[m*64 + o], acc);
        if (out_cat) out_cat[(size_t)nidx*112 + f] = acc;
        else         out_s[(size_t)nidx*64 + o] = acc;
    }
}

// ---------------- host launcher ----------------
extern "C" void kernel_launch(void* const* d_in, const int* in_sizes, int n_in,
                              void* d_out, int out_size, void* d_ws, size_t ws_size,
                              hipStream_t stream) {
    const float* in_s  = (const float*)d_in[0];
    const float* in_v  = (const float*)d_in[1];
    const int*   snd   = (const int*)  d_in[2];
    const int*   rcv   = (const int*)  d_in[3];
    const float* e1_ws = (const float*)d_in[4];
    const float* e1_b  = (const float*)d_in[5];
    const float* e1_wv = (const float*)d_in[6];
    const float* e2_ws = (const float*)d_in[7];
    const float* e2_b  = (const float*)d_in[8];
    const float* e2_wv = (const float*)d_in[9];
    const float* n_ws  = (const float*)d_in[10];
    const float* n_b   = (const float*)d_in[11];
    const float* n_wv  = (const float*)d_in[12];
    const float* l_ws  = (const float*)d_in[13];
    const float* l_b   = (const float*)d_in[14];
    const float* l_wv  = (const float*)d_in[15];

    float* ws    = (float*)d_ws;
    float* cur_s = ws;                           // N*64
    float* cur_v = cur_s + 262144;               // N*48
    float* nxt_s = cur_v + 196608;               // N*64
    float* nxt_v = nxt_s + 262144;               // N*48
    float* sum_s = nxt_v + 196608;               // N*64
    float* sum_v = sum_s + 262144;               // N*48
    float* sum_u = sum_v + 196608;               // N*3
    float* cnt   = sum_u + 12288;                // N
    float* y_s   = cnt + 4096;                   // N*65
    float* y_v   = y_s + 266240;                 // N*51

    // zero accumulators (sum_s, sum_v, sum_u, cnt are contiguous)
    hipMemsetAsync(sum_s, 0, (size_t)(262144 + 196608 + 12288 + 4096) * sizeof(float), stream);
    hipMemcpyAsync(cur_s, in_s, (size_t)262144 * sizeof(float), hipMemcpyDeviceToDevice, stream);
    hipMemcpyAsync(cur_v, in_v, (size_t)196608 * sizeof(float), hipMemcpyDeviceToDevice, stream);
    segnn_cnt_kernel<<<EDG/256, 256, 0, stream>>>(rcv, cnt);

    for (int step = 0; step < 3; ++step) {
        segnn_edge_fused<<<EDG/64, 256, 0, stream>>>(cur_s, cur_v, snd, rcv,
            e1_ws + (size_t)step*160*80, e1_b + step*80, e1_wv + (size_t)step*160*16,
            e2_ws + (size_t)(step*2+0)*80*80, e2_b + (step*2+0)*80, e2_wv + (size_t)(step*2+0)*80*16,
            e2_ws + (size_t)(step*2+1)*80*80, e2_b + (step*2+1)*80, e2_wv + (size_t)(step*2+1)*80*16,
            sum_s, sum_v, sum_u);
        segnn_y_kernel<<<NND, 128, 0, stream>>>(sum_s, sum_v, sum_u, cnt, y_s, y_v);

        segnn_node_kernel<<<NND/16, 512, 0, stream>>>(cur_s, cur_v, y_s, y_v,
            n_ws + (size_t)(step*3+0)*4432*80, n_b + (step*3+0)*80, n_wv + (size_t)(step*3+0)*2128*16,
            nxt_s, nxt_v);
        segnn_node_kernel<<<NND/16, 512, 0, stream>>>(nxt_s, nxt_v, y_s, y_v,
            n_ws + (size_t)(step*3+1)*4432*80, n_b + (step*3+1)*80, n_wv + (size_t)(step*3+1)*2128*16,
            cur_s, cur_v);
        segnn_node_kernel<<<NND/16, 512, 0, stream>>>(cur_s, cur_v, y_s, y_v,
            n_ws + (size_t)(step*3+2)*4432*80, n_b + (step*3+2)*80, n_wv + (size_t)(step*3+2)*2128*16,
            nxt_s, nxt_v);

        segnn_linear_kernel<<<(NND*112 + 255)/256, 256, 0, stream>>>(nxt_s, nxt_v,
            l_ws + (size_t)step*64*64, l_b + step*64, l_wv + (size_t)step*16*16,
            cur_s, cur_v, (step == 2) ? (float*)d_out : nullptr);
    }
}

// Round 3
// 2079.090 us; speedup vs baseline: 1.5003x; 1.2280x over previous
//
#include <hip/hip_runtime.h>
#include <math.h>

// ---------------- problem constants ----------------
constexpr int NND = 4096;     // nodes
constexpr int EDG = 32768;    // edges
constexpr float SQRT3  = 1.7320508075688772f;
constexpr float ISQRT3 = 0.5773502691896258f;
constexpr float NORMI  = 1.0f / 32767.0f;   // 1/(E-1)

__device__ __forceinline__ float gelu_f(float x) {
    float x3 = x * x * x;
    return 0.5f * x * (1.0f + tanhf(0.7978845608028654f * (x + 0.044715f * x3)));
}
__device__ __forceinline__ float sigmoid_f(float x) {
    return 1.0f / (1.0f + expf(-x));
}

// acc[4*NO4] += x * w[0..4*NO4)
template<int NO4>
__device__ __forceinline__ void rank1(float* acc, float x, const float* w) {
#pragma unroll
    for (int u = 0; u < NO4; ++u) {
        const float4 q = *reinterpret_cast<const float4*>(w + 4 * u);
        acc[4*u+0] = fmaf(x, q.x, acc[4*u+0]);
        acc[4*u+1] = fmaf(x, q.y, acc[4*u+1]);
        acc[4*u+2] = fmaf(x, q.z, acc[4*u+2]);
        acc[4*u+3] = fmaf(x, q.w, acc[4*u+3]);
    }
}

// av[48] (16 outputs x 3 comps) += (t0,t1,t2) outer w[0..16)
__device__ __forceinline__ void rank1v(float* av, float t0, float t1, float t2, const float* wk) {
#pragma unroll
    for (int u = 0; u < 4; ++u) {
        const float4 q = *reinterpret_cast<const float4*>(wk + 4 * u);
        const float w0 = q.x, w1 = q.y, w2 = q.z, w3 = q.w;
        av[(4*u+0)*3+0] = fmaf(t0, w0, av[(4*u+0)*3+0]);
        av[(4*u+0)*3+1] = fmaf(t1, w0, av[(4*u+0)*3+1]);
        av[(4*u+0)*3+2] = fmaf(t2, w0, av[(4*u+0)*3+2]);
        av[(4*u+1)*3+0] = fmaf(t0, w1, av[(4*u+1)*3+0]);
        av[(4*u+1)*3+1] = fmaf(t1, w1, av[(4*u+1)*3+1]);
        av[(4*u+1)*3+2] = fmaf(t2, w1, av[(4*u+1)*3+2]);
        av[(4*u+2)*3+0] = fmaf(t0, w2, av[(4*u+2)*3+0]);
        av[(4*u+2)*3+1] = fmaf(t1, w2, av[(4*u+2)*3+1]);
        av[(4*u+2)*3+2] = fmaf(t2, w2, av[(4*u+2)*3+2]);
        av[(4*u+3)*3+0] = fmaf(t0, w3, av[(4*u+3)*3+0]);
        av[(4*u+3)*3+1] = fmaf(t1, w3, av[(4*u+3)*3+1]);
        av[(4*u+3)*3+2] = fmaf(t2, w3, av[(4*u+3)*3+2]);
    }
}

// ---------------- CSR construction (once per launch) ----------------
__global__ __launch_bounds__(256)
void segnn_deg_kernel(const int* __restrict__ rcv, int* __restrict__ deg) {
    const int e = blockIdx.x * 256 + threadIdx.x;
    if (e < EDG) atomicAdd(deg + rcv[e], 1);
}

__global__ __launch_bounds__(1024)
void segnn_scan_kernel(const int* __restrict__ deg, int* __restrict__ off) {
    __shared__ int tots[1024];
    const int t = threadIdx.x;
    const int v0 = deg[4*t], v1 = deg[4*t+1], v2 = deg[4*t+2], v3 = deg[4*t+3];
    const int p1 = v0, p2 = p1 + v1, p3 = p2 + v2, p4 = p3 + v3;
    tots[t] = p4;
    __syncthreads();
    for (int d = 1; d < 1024; d <<= 1) {
        const int add = (t >= d) ? tots[t - d] : 0;
        __syncthreads();
        tots[t] += add;
        __syncthreads();
    }
    const int excl = t ? tots[t-1] : 0;
    off[4*t+0] = excl;
    off[4*t+1] = excl + p1;
    off[4*t+2] = excl + p2;
    off[4*t+3] = excl + p3;
    if (t == 1023) off[4096] = tots[1023];
}

__global__ __launch_bounds__(256)
void segnn_scatter_kernel(const int* __restrict__ rcv, const int* __restrict__ off,
                          int* __restrict__ cursor, int* __restrict__ elist) {
    const int e = blockIdx.x * 256 + threadIdx.x;
    if (e < EDG) {
        const int j = rcv[e];
        const int p = atomicAdd(cursor + j, 1);
        elist[off[j] + p] = e;
    }
}

// ---------------- fused edge pipeline (blocks 0,1,2 -> msg) ----------------
// 256 threads = 64 edges x 4 threads/edge. Thread h owns scalar cols [20h,20h+20)
// and vector cols [4h,4h+4). Intermediates live in LDS; final msg written coalesced.
template<int NSX, int NVX>
__device__ __forceinline__ void edge_phase(int e, int h, float ux, float uy, float uz,
                                           const float XS[64][129], const float XV[64][97],
                                           const float* __restrict__ Ws,
                                           const float* __restrict__ B,
                                           const float* __restrict__ Wv,
                                           float* acc, float* accu, float* accv) {
#pragma unroll
    for (int u = 0; u < 20; ++u) acc[u] = B[20*h + u];
#pragma unroll
    for (int u = 0; u < 4; ++u) accu[u] = 0.0f;
#pragma unroll
    for (int u = 0; u < 12; ++u) accv[u] = 0.0f;
    const float* wsr = Ws + 20*h;
    const float* wvr = Wv + 4*h;
#pragma unroll 4
    for (int m = 0; m < NSX; ++m) {
        const float x = XS[e][m];
        rank1<5>(acc,  x, wsr + (size_t)m*80);
        rank1<1>(accu, x, wvr + (size_t)m*16);
    }
#pragma unroll 2
    for (int m = 0; m < NVX; ++m) {
        const float a0 = XV[e][3*m+0], a1 = XV[e][3*m+1], a2 = XV[e][3*m+2];
        const float p = a0*ux + a1*uy + a2*uz;
        rank1<5>(acc, p, wsr + (size_t)(NSX+m)*80);
        const float4 wq = *reinterpret_cast<const float4*>(wvr + (size_t)(NSX+m)*16);
        const float wk[4] = { wq.x, wq.y, wq.z, wq.w };
#pragma unroll
        for (int oo = 0; oo < 4; ++oo) {
            accv[oo*3+0] = fmaf(a0, wk[oo], accv[oo*3+0]);
            accv[oo*3+1] = fmaf(a1, wk[oo], accv[oo*3+1]);
            accv[oo*3+2] = fmaf(a2, wk[oo], accv[oo*3+2]);
        }
    }
}

__global__ __launch_bounds__(256, 2)
void segnn_edge_fused(const float* __restrict__ cs, const float* __restrict__ cv,
                      const int* __restrict__ snd, const int* __restrict__ rcv,
                      const float* __restrict__ W0s, const float* __restrict__ B0, const float* __restrict__ W0v,
                      const float* __restrict__ W1s, const float* __restrict__ B1, const float* __restrict__ W1v,
                      const float* __restrict__ W2s, const float* __restrict__ B2, const float* __restrict__ W2v,
                      float* __restrict__ msg) {
    __shared__ float XS[64][129];   // scalar x (phase0: 128 = s_i|s_j; later: 64)
    __shared__ float XV[64][97];    // vector x (phase0: 96 = v_i|v_j; later: 48)
    __shared__ float UU[64][4];     // unit vector per edge
    __shared__ float GG[64][16];    // raw gate pre-activations (h=3 -> all)

    const int tid = threadIdx.x;
    const int e0  = blockIdx.x * 64;

    for (int idx = tid; idx < 64*128; idx += 256) {
        const int e = idx >> 7, m = idx & 127;
        const int node = (m < 64) ? snd[e0+e] : rcv[e0+e];
        XS[e][m] = cs[(size_t)node*64 + (m & 63)];
    }
    for (int idx = tid; idx < 64*96; idx += 256) {
        const int e = idx / 96, m = idx - e*96;
        const int node = (m < 48) ? snd[e0+e] : rcv[e0+e];
        XV[e][m] = cv[(size_t)node*48 + (m < 48 ? m : m - 48)];
    }
    __syncthreads();
    if (tid < 64) {
        const float rx = XV[tid][0]-XV[tid][48], ry = XV[tid][1]-XV[tid][49], rz = XV[tid][2]-XV[tid][50];
        const float rinv = 1.0f / fmaxf(sqrtf(rx*rx+ry*ry+rz*rz), 1e-9f);
        UU[tid][0] = rx*rinv; UU[tid][1] = ry*rinv; UU[tid][2] = rz*rinv;
    }
    __syncthreads();

    const int e = tid >> 2, h = tid & 3;
    const float ux = UU[e][0], uy = UU[e][1], uz = UU[e][2];
    float acc[20], accu[4], accv[12];

    // ---- phase 0 (E1 = 160 rows) ----
    edge_phase<128,32>(e, h, ux, uy, uz, XS, XV, W0s, B0, W0v, acc, accu, accv);
    __syncthreads();                           // all reads of XS/XV done
    if (h == 3) {
#pragma unroll
        for (int u = 0; u < 16; ++u) GG[e][u] = acc[4+u];
    }
    {
        const int ns = (h == 3) ? 4 : 20;
        for (int u = 0; u < ns; ++u) XS[e][20*h + u] = gelu_f(acc[u]);
    }
    __syncthreads();                           // gates + scalars visible
#pragma unroll
    for (int oo = 0; oo < 4; ++oo) {
        const float g  = sigmoid_f(GG[e][4*h + oo]);
        const float uo = accu[oo] * SQRT3;
        XV[e][(4*h+oo)*3+0] = fmaf(uo, ux, accv[oo*3+0]) * g;
        XV[e][(4*h+oo)*3+1] = fmaf(uo, uy, accv[oo*3+1]) * g;
        XV[e][(4*h+oo)*3+2] = fmaf(uo, uz, accv[oo*3+2]) * g;
    }
    __syncthreads();

    // ---- phase 1 (E2 = 80 rows) ----
    edge_phase<64,16>(e, h, ux, uy, uz, XS, XV, W1s, B1, W1v, acc, accu, accv);
    __syncthreads();
    if (h == 3) {
#pragma unroll
        for (int u = 0; u < 16; ++u) GG[e][u] = acc[4+u];
    }
    {
        const int ns = (h == 3) ? 4 : 20;
        for (int u = 0; u < ns; ++u) XS[e][20*h + u] = gelu_f(acc[u]);
    }
    __syncthreads();
#pragma unroll
    for (int oo = 0; oo < 4; ++oo) {
        const float g  = sigmoid_f(GG[e][4*h + oo]);
        const float uo = accu[oo] * SQRT3;
        XV[e][(4*h+oo)*3+0] = fmaf(uo, ux, accv[oo*3+0]) * g;
        XV[e][(4*h+oo)*3+1] = fmaf(uo, uy, accv[oo*3+1]) * g;
        XV[e][(4*h+oo)*3+2] = fmaf(uo, uz, accv[oo*3+2]) * g;
    }
    __syncthreads();

    // ---- phase 2 (E2 = 80 rows) + staged coalesced message write ----
    edge_phase<64,16>(e, h, ux, uy, uz, XS, XV, W2s, B2, W2v, acc, accu, accv);
    __syncthreads();
    if (h == 3) {
#pragma unroll
        for (int u = 0; u < 16; ++u) GG[e][u] = acc[4+u];
    }
    {
        const int ns = (h == 3) ? 4 : 20;
        for (int u = 0; u < ns; ++u) XS[e][20*h + u] = gelu_f(acc[u]);
    }
    __syncthreads();
#pragma unroll
    for (int oo = 0; oo < 4; ++oo) {
        const float g  = sigmoid_f(GG[e][4*h + oo]);
        const float uo = accu[oo] * SQRT3;
        XV[e][(4*h+oo)*3+0] = fmaf(uo, ux, accv[oo*3+0]) * g;
        XV[e][(4*h+oo)*3+1] = fmaf(uo, uy, accv[oo*3+1]) * g;
        XV[e][(4*h+oo)*3+2] = fmaf(uo, uz, accv[oo*3+2]) * g;
    }
    __syncthreads();
    for (int idx = tid; idx < 64*115; idx += 256) {
        const int e2 = idx / 115, f = idx - e2*115;
        float vv;
        if (f < 64)       vv = XS[e2][f];
        else if (f < 112) vv = XV[e2][f-64];
        else              vv = UU[e2][f-112];
        msg[(size_t)(e0+e2)*116 + f] = vv;
    }
}

// ---------------- gather: CSR segment-mean -> y ----------------
__global__ __launch_bounds__(128)
void segnn_gather_kernel(const float* __restrict__ msg, const int* __restrict__ off,
                         const int* __restrict__ elist,
                         float* __restrict__ y_s, float* __restrict__ y_v) {
    const int n = blockIdx.x, f = threadIdx.x;
    const int o0 = off[n], o1 = off[n+1];
    const int deg = o1 - o0;
    float acc = 0.0f;
    for (int p = o0; p < o1; ++p) {
        const int eid = elist[p];
        if (f < 115) acc += msg[(size_t)eid*116 + f];
    }
    const float inv = NORMI / (float)(deg > 0 ? deg : 1);
    if (f < 64)        y_s[(size_t)n*65 + f] = acc * inv;
    else if (f < 112)  y_v[(size_t)n*51 + (f-64)] = acc * inv;
    else if (f < 115)  y_v[(size_t)n*51 + 48 + (f-112)] = SQRT3 * acc * inv;
    else if (f == 115) y_s[(size_t)n*65 + 64] = deg ? NORMI : 0.0f;
}

// ---------------- node TP-gate block ----------------
// 1024 threads: 16 nodes x 32 K-slices x 2 column-passes -> 4 waves/SIMD.
__global__ __launch_bounds__(1024)
void segnn_node_kernel(const float* __restrict__ in_s, const float* __restrict__ in_v,
                       const float* __restrict__ y_s, const float* __restrict__ y_v,
                       const float* __restrict__ W,  const float* __restrict__ B,
                       const float* __restrict__ Wv,
                       float* __restrict__ out_s, float* __restrict__ out_v) {
    __shared__ float xs[16][65];
    __shared__ float xv[16][49];
    __shared__ float ysL[16][65];
    __shared__ float yvL[16][53];
    __shared__ float red[16][16][49];
    __shared__ float fin_s[16][81];
    __shared__ float fin_v[16][49];

    const int tid = threadIdx.x;
    const int nb0 = blockIdx.x * 16;
    for (int idx = tid; idx < 16*64; idx += 1024) { const int n = idx >> 6, m = idx & 63; xs[n][m] = in_s[(size_t)(nb0+n)*64 + m]; }
    for (int idx = tid; idx < 16*48; idx += 1024) { const int n = idx / 48, m = idx - n*48; xv[n][m] = in_v[(size_t)(nb0+n)*48 + m]; }
    for (int idx = tid; idx < 16*65; idx += 1024) { const int n = idx / 65, m = idx - n*65; ysL[n][m] = y_s[(size_t)(nb0+n)*65 + m]; }
    for (int idx = tid; idx < 16*51; idx += 1024) { const int n = idx / 51, m = idx - n*51; yvL[n][m] = y_v[(size_t)(nb0+n)*51 + m]; }
    __syncthreads();

    const int n = tid & 15, slice = (tid >> 4) & 31, pass = tid >> 9;
    const int lane = tid & 63, w = tid >> 6;       // wave 0..15 (0-7 pass0, 8-15 pass1)
    const int ob = 40 * pass;
    const int dm  = slice >> 1;                    // dd: m per slice-pair, k halves
    const int dk0 = (slice & 1) ? 9 : 0,  dk1 = (slice & 1) ? 17 : 9;

    // ---- scalar outputs: this thread's 40 columns [ob, ob+40) ----
    {
        float acc[40];
#pragma unroll
        for (int u = 0; u < 40; ++u) acc[u] = 0.0f;
        // ss rows: m in {2*slice, 2*slice+1}, all k<65
#pragma unroll 1
        for (int mi = 0; mi < 2; ++mi) {
            const int m = 2*slice + mi;
            const float xm = xs[n][m];
            const float* wr = W + (size_t)(m*65) * 80 + ob;
#pragma unroll 2
            for (int k = 0; k < 65; ++k) {
                const float x = xm * ysL[n][k];
                rank1<10>(acc, x, wr + k*80);
            }
        }
        // dd rows
        {
            const float v0 = xv[n][dm*3+0], v1 = xv[n][dm*3+1], v2 = xv[n][dm*3+2];
            const float* wr = W + (size_t)(4160 + dm*17) * 80 + ob;
#pragma unroll 2
            for (int k = dk0; k < dk1; ++k) {
                const float x = (v0*yvL[n][k*3+0] + v1*yvL[n][k*3+1] + v2*yvL[n][k*3+2]) * ISQRT3;
                rank1<10>(acc, x, wr + k*80);
            }
        }
        // reduce 4 slices within wave (lane bits 4,5)
#pragma unroll
        for (int u = 0; u < 40; ++u) {
            acc[u] += __shfl_xor(acc[u], 16);
            acc[u] += __shfl_xor(acc[u], 32);
        }
        if (lane < 16) {
#pragma unroll
            for (int u = 0; u < 40; ++u) red[w][lane][u] = acc[u];
        }
        __syncthreads();
        for (int idx = tid; idx < 16*80; idx += 1024) {
            const int nn = idx / 80, cc = idx - nn*80;
            const int p = cc >= 40 ? 1 : 0, oo = cc - 40*p;
            float s = 0.0f;
#pragma unroll
            for (int ww = 0; ww < 8; ++ww) s += red[8*p + ww][nn][oo];
            fin_s[nn][cc] = s + B[cc];
        }
        __syncthreads();
    }

    // ---- vector outputs: pass0 threads do sv, pass1 threads do vs ----
    {
        float av[48];
#pragma unroll
        for (int u = 0; u < 48; ++u) av[u] = 0.0f;
        if (pass == 0) {
            // sv rows: m in {2*slice, 2*slice+1}, k<17;  X = s[m]*yv[k,:]
#pragma unroll 1
            for (int mi = 0; mi < 2; ++mi) {
                const int m = 2*slice + mi;
                const float xm = xs[n][m];
                const float* wr = Wv + (size_t)(m*17) * 16;
#pragma unroll 2
                for (int k = 0; k < 17; ++k) {
                    rank1v(av, xm*yvL[n][k*3+0], xm*yvL[n][k*3+1], xm*yvL[n][k*3+2], wr + k*16);
                }
            }
        } else {
            // vs rows: m = slice>>1, k half;  X = v[m,:]*ys[k]
            const int vm  = slice >> 1;
            const int vk0 = (slice & 1) ? 33 : 0, vk1 = (slice & 1) ? 65 : 33;
            const float b0 = xv[n][vm*3+0], b1 = xv[n][vm*3+1], b2 = xv[n][vm*3+2];
            const float* wr = Wv + (size_t)(1088 + vm*65) * 16;
#pragma unroll 2
            for (int k = vk0; k < vk1; ++k) {
                const float yk = ysL[n][k];
                rank1v(av, b0*yk, b1*yk, b2*yk, wr + k*16);
            }
        }
#pragma unroll
        for (int u = 0; u < 48; ++u) {
            av[u] += __shfl_xor(av[u], 16);
            av[u] += __shfl_xor(av[u], 32);
        }
        if (lane < 16) {
#pragma unroll
            for (int u = 0; u < 48; ++u) red[w][lane][u] = av[u];
        }
        __syncthreads();
        for (int idx = tid; idx < 16*48; idx += 1024) {
            const int nn = idx / 48, oo = idx - nn*48;
            float s = 0.0f;
#pragma unroll
            for (int ww = 0; ww < 16; ++ww) s += red[ww][nn][oo];
            fin_v[nn][oo] = s;
        }
        __syncthreads();
    }

    // ---- epilogue: gelu / sigmoid-gate, write ----
    for (int idx = tid; idx < 16*112; idx += 1024) {
        const int nn = idx / 112, f = idx - nn*112;
        if (f < 64) {
            out_s[(size_t)(nb0+nn)*64 + f] = gelu_f(fin_s[nn][f]);
        } else {
            const int r = f - 64;
            const int o = r / 3;
            const float gg = sigmoid_f(fin_s[nn][64 + o]);
            out_v[(size_t)(nb0+nn)*48 + r] = fin_v[nn][r] * gg;
        }
    }
}

// ---------------- per-step final Linear ----------------
__global__ __launch_bounds__(256)
void segnn_linear_kernel(const float* __restrict__ in_s, const float* __restrict__ in_v,
                         const float* __restrict__ lws, const float* __restrict__ lb,
                         const float* __restrict__ lwv,
                         float* __restrict__ out_s, float* __restrict__ out_v,
                         float* __restrict__ out_cat) {
    const int idx = blockIdx.x * 256 + threadIdx.x;
    if (idx >= NND * 112) return;
    const int nidx = idx / 112, f = idx - nidx * 112;
    if (f < 48) {
        const int k = f / 3, d = f - 3*k;
        const float* vp = in_v + (size_t)nidx * 48 + d;
        float acc = 0.0f;
#pragma unroll
        for (int m = 0; m < 16; ++m) acc = fmaf(vp[m*3], lwv[m*16 + k], acc);
        if (out_cat) out_cat[(size_t)nidx*112 + f] = acc;
        else         out_v[(size_t)nidx*48 + f] = acc;
    } else {
        const int o = f - 48;
        const float* sp = in_s + (size_t)nidx * 64;
        float acc = lb[o];
#pragma unroll
        for (int m = 0; m < 64; ++m) acc = fmaf(sp[m], lws[m*64 + o], acc);
        if (out_cat) out_cat[(size_t)nidx*112 + f] = acc;
        else         out_s[(size_t)nidx*64 + o] = acc;
    }
}

// ---------------- host launcher ----------------
extern "C" void kernel_launch(void* const* d_in, const int* in_sizes, int n_in,
                              void* d_out, int out_size, void* d_ws, size_t ws_size,
                              hipStream_t stream) {
    const float* in_s  = (const float*)d_in[0];
    const float* in_v  = (const float*)d_in[1];
    const int*   snd   = (const int*)  d_in[2];
    const int*   rcv   = (const int*)  d_in[3];
    const float* e1_ws = (const float*)d_in[4];
    const float* e1_b  = (const float*)d_in[5];
    const float* e1_wv = (const float*)d_in[6];
    const float* e2_ws = (const float*)d_in[7];
    const float* e2_b  = (const float*)d_in[8];
    const float* e2_wv = (const float*)d_in[9];
    const float* n_ws  = (const float*)d_in[10];
    const float* n_b   = (const float*)d_in[11];
    const float* n_wv  = (const float*)d_in[12];
    const float* l_ws  = (const float*)d_in[13];
    const float* l_b   = (const float*)d_in[14];
    const float* l_wv  = (const float*)d_in[15];

    float* ws    = (float*)d_ws;
    float* cur_s = ws;                           // N*64   = 262144
    float* cur_v = cur_s + 262144;               // N*48   = 196608
    float* nxt_s = cur_v + 196608;               // N*64
    float* nxt_v = nxt_s + 262144;               // N*48
    float* y_s   = nxt_v + 196608;               // N*65   = 266240
    float* y_v   = y_s + 266240;                 // N*51   = 208896
    float* msg   = y_v + 208896;                 // E*116  = 3801088
    int*   deg    = (int*)(msg + 3801088);       // N
    int*   cursor = deg + 4096;                  // N
    int*   off    = cursor + 4096;               // N+1
    int*   elist  = off + 4097;                  // E

    // CSR build (deg+cursor zeroed each launch; identical work every call)
    hipMemsetAsync(deg, 0, (size_t)8192 * sizeof(int), stream);
    hipMemcpyAsync(cur_s, in_s, (size_t)262144 * sizeof(float), hipMemcpyDeviceToDevice, stream);
    hipMemcpyAsync(cur_v, in_v, (size_t)196608 * sizeof(float), hipMemcpyDeviceToDevice, stream);
    segnn_deg_kernel<<<EDG/256, 256, 0, stream>>>(rcv, deg);
    segnn_scan_kernel<<<1, 1024, 0, stream>>>(deg, off);
    segnn_scatter_kernel<<<EDG/256, 256, 0, stream>>>(rcv, off, cursor, elist);

    for (int step = 0; step < 3; ++step) {
        segnn_edge_fused<<<EDG/64, 256, 0, stream>>>(cur_s, cur_v, snd, rcv,
            e1_ws + (size_t)step*160*80, e1_b + step*80, e1_wv + (size_t)step*160*16,
            e2_ws + (size_t)(step*2+0)*80*80, e2_b + (step*2+0)*80, e2_wv + (size_t)(step*2+0)*80*16,
            e2_ws + (size_t)(step*2+1)*80*80, e2_b + (step*2+1)*80, e2_wv + (size_t)(step*2+1)*80*16,
            msg);
        segnn_gather_kernel<<<NND, 128, 0, stream>>>(msg, off, elist, y_s, y_v);

        segnn_node_kernel<<<NND/16, 1024, 0, stream>>>(cur_s, cur_v, y_s, y_v,
            n_ws + (size_t)(step*3+0)*4432*80, n_b + (step*3+0)*80, n_wv + (size_t)(step*3+0)*2128*16,
            nxt_s, nxt_v);
        segnn_node_kernel<<<NND/16, 1024, 0, stream>>>(nxt_s, nxt_v, y_s, y_v,
            n_ws + (size_t)(step*3+1)*4432*80, n_b + (step*3+1)*80, n_wv + (size_t)(step*3+1)*2128*16,
            cur_s, cur_v);
        segnn_node_kernel<<<NND/16, 1024, 0, stream>>>(cur_s, cur_v, y_s, y_v,
            n_ws + (size_t)(step*3+2)*4432*80, n_b + (step*3+2)*80, n_wv + (size_t)(step*3+2)*2128*16,
            nxt_s, nxt_v);

        segnn_linear_kernel<<<(NND*112 + 255)/256, 256, 0, stream>>>(nxt_s, nxt_v,
            l_ws + (size_t)step*64*64, l_b + step*64, l_wv + (size_t)step*16*16,
            cur_s, cur_v, (step == 2) ? (float*)d_out : nullptr);
    }
}

// Round 4
// 1257.979 us; speedup vs baseline: 2.4795x; 1.6527x over previous
//
#include <hip/hip_runtime.h>
#include <math.h>

// ---------------- problem constants ----------------
constexpr int NND = 4096;     // nodes
constexpr int EDG = 32768;    // edges
constexpr float SQRT3  = 1.7320508075688772f;
constexpr float ISQRT3 = 0.5773502691896258f;
constexpr float NORMI  = 1.0f / 32767.0f;   // 1/(E-1)

__device__ __forceinline__ float gelu_f(float x) {
    float x3 = x * x * x;
    return 0.5f * x * (1.0f + tanhf(0.7978845608028654f * (x + 0.044715f * x3)));
}
__device__ __forceinline__ float sigmoid_f(float x) {
    return 1.0f / (1.0f + expf(-x));
}

// acc[4*NO4] += x * w[0..4*NO4)
template<int NO4>
__device__ __forceinline__ void rank1(float* acc, float x, const float* w) {
#pragma unroll
    for (int u = 0; u < NO4; ++u) {
        const float4 q = *reinterpret_cast<const float4*>(w + 4 * u);
        acc[4*u+0] = fmaf(x, q.x, acc[4*u+0]);
        acc[4*u+1] = fmaf(x, q.y, acc[4*u+1]);
        acc[4*u+2] = fmaf(x, q.z, acc[4*u+2]);
        acc[4*u+3] = fmaf(x, q.w, acc[4*u+3]);
    }
}

// ---------------- CSR construction (once per launch) ----------------
__global__ __launch_bounds__(256)
void segnn_deg_kernel(const int* __restrict__ rcv, int* __restrict__ deg) {
    const int e = blockIdx.x * 256 + threadIdx.x;
    if (e < EDG) atomicAdd(deg + rcv[e], 1);
}

__global__ __launch_bounds__(1024)
void segnn_scan_kernel(const int* __restrict__ deg, int* __restrict__ off) {
    __shared__ int tots[1024];
    const int t = threadIdx.x;
    const int v0 = deg[4*t], v1 = deg[4*t+1], v2 = deg[4*t+2], v3 = deg[4*t+3];
    const int p1 = v0, p2 = p1 + v1, p3 = p2 + v2, p4 = p3 + v3;
    tots[t] = p4;
    __syncthreads();
    for (int d = 1; d < 1024; d <<= 1) {
        const int add = (t >= d) ? tots[t - d] : 0;
        __syncthreads();
        tots[t] += add;
        __syncthreads();
    }
    const int excl = t ? tots[t-1] : 0;
    off[4*t+0] = excl;
    off[4*t+1] = excl + p1;
    off[4*t+2] = excl + p2;
    off[4*t+3] = excl + p3;
    if (t == 1023) off[4096] = tots[1023];
}

__global__ __launch_bounds__(256)
void segnn_scatter_kernel(const int* __restrict__ rcv, const int* __restrict__ off,
                          int* __restrict__ cursor, int* __restrict__ elist) {
    const int e = blockIdx.x * 256 + threadIdx.x;
    if (e < EDG) {
        const int j = rcv[e];
        const int p = atomicAdd(cursor + j, 1);
        elist[off[j] + p] = e;
    }
}

// ---------------- fused edge pipeline (blocks 0,1,2 -> msg) ----------------
template<int NSX, int NVX>
__device__ __forceinline__ void edge_phase(int e, int h, float ux, float uy, float uz,
                                           const float XS[64][129], const float XV[64][97],
                                           const float* __restrict__ Ws,
                                           const float* __restrict__ B,
                                           const float* __restrict__ Wv,
                                           float* acc, float* accu, float* accv) {
#pragma unroll
    for (int u = 0; u < 20; ++u) acc[u] = B[20*h + u];
#pragma unroll
    for (int u = 0; u < 4; ++u) accu[u] = 0.0f;
#pragma unroll
    for (int u = 0; u < 12; ++u) accv[u] = 0.0f;
    const float* wsr = Ws + 20*h;
    const float* wvr = Wv + 4*h;
#pragma unroll 4
    for (int m = 0; m < NSX; ++m) {
        const float x = XS[e][m];
        rank1<5>(acc,  x, wsr + (size_t)m*80);
        rank1<1>(accu, x, wvr + (size_t)m*16);
    }
#pragma unroll 2
    for (int m = 0; m < NVX; ++m) {
        const float a0 = XV[e][3*m+0], a1 = XV[e][3*m+1], a2 = XV[e][3*m+2];
        const float p = a0*ux + a1*uy + a2*uz;
        rank1<5>(acc, p, wsr + (size_t)(NSX+m)*80);
        const float4 wq = *reinterpret_cast<const float4*>(wvr + (size_t)(NSX+m)*16);
        const float wk[4] = { wq.x, wq.y, wq.z, wq.w };
#pragma unroll
        for (int oo = 0; oo < 4; ++oo) {
            accv[oo*3+0] = fmaf(a0, wk[oo], accv[oo*3+0]);
            accv[oo*3+1] = fmaf(a1, wk[oo], accv[oo*3+1]);
            accv[oo*3+2] = fmaf(a2, wk[oo], accv[oo*3+2]);
        }
    }
}

__global__ __launch_bounds__(256, 2)
void segnn_edge_fused(const float* __restrict__ cs, const float* __restrict__ cv,
                      const int* __restrict__ snd, const int* __restrict__ rcv,
                      const float* __restrict__ W0s, const float* __restrict__ B0, const float* __restrict__ W0v,
                      const float* __restrict__ W1s, const float* __restrict__ B1, const float* __restrict__ W1v,
                      const float* __restrict__ W2s, const float* __restrict__ B2, const float* __restrict__ W2v,
                      float* __restrict__ msg) {
    __shared__ float XS[64][129];
    __shared__ float XV[64][97];
    __shared__ float UU[64][4];
    __shared__ float GG[64][16];

    const int tid = threadIdx.x;
    const int e0  = blockIdx.x * 64;

    for (int idx = tid; idx < 64*128; idx += 256) {
        const int e = idx >> 7, m = idx & 127;
        const int node = (m < 64) ? snd[e0+e] : rcv[e0+e];
        XS[e][m] = cs[(size_t)node*64 + (m & 63)];
    }
    for (int idx = tid; idx < 64*96; idx += 256) {
        const int e = idx / 96, m = idx - e*96;
        const int node = (m < 48) ? snd[e0+e] : rcv[e0+e];
        XV[e][m] = cv[(size_t)node*48 + (m < 48 ? m : m - 48)];
    }
    __syncthreads();
    if (tid < 64) {
        const float rx = XV[tid][0]-XV[tid][48], ry = XV[tid][1]-XV[tid][49], rz = XV[tid][2]-XV[tid][50];
        const float rinv = 1.0f / fmaxf(sqrtf(rx*rx+ry*ry+rz*rz), 1e-9f);
        UU[tid][0] = rx*rinv; UU[tid][1] = ry*rinv; UU[tid][2] = rz*rinv;
    }
    __syncthreads();

    const int e = tid >> 2, h = tid & 3;
    const float ux = UU[e][0], uy = UU[e][1], uz = UU[e][2];
    float acc[20], accu[4], accv[12];

    // ---- phase 0 (E1 = 160 rows) ----
    edge_phase<128,32>(e, h, ux, uy, uz, XS, XV, W0s, B0, W0v, acc, accu, accv);
    __syncthreads();
    if (h == 3) {
#pragma unroll
        for (int u = 0; u < 16; ++u) GG[e][u] = acc[4+u];
    }
    {
        const int ns = (h == 3) ? 4 : 20;
        for (int u = 0; u < ns; ++u) XS[e][20*h + u] = gelu_f(acc[u]);
    }
    __syncthreads();
#pragma unroll
    for (int oo = 0; oo < 4; ++oo) {
        const float g  = sigmoid_f(GG[e][4*h + oo]);
        const float uo = accu[oo] * SQRT3;
        XV[e][(4*h+oo)*3+0] = fmaf(uo, ux, accv[oo*3+0]) * g;
        XV[e][(4*h+oo)*3+1] = fmaf(uo, uy, accv[oo*3+1]) * g;
        XV[e][(4*h+oo)*3+2] = fmaf(uo, uz, accv[oo*3+2]) * g;
    }
    __syncthreads();

    // ---- phase 1 (E2 = 80 rows) ----
    edge_phase<64,16>(e, h, ux, uy, uz, XS, XV, W1s, B1, W1v, acc, accu, accv);
    __syncthreads();
    if (h == 3) {
#pragma unroll
        for (int u = 0; u < 16; ++u) GG[e][u] = acc[4+u];
    }
    {
        const int ns = (h == 3) ? 4 : 20;
        for (int u = 0; u < ns; ++u) XS[e][20*h + u] = gelu_f(acc[u]);
    }
    __syncthreads();
#pragma unroll
    for (int oo = 0; oo < 4; ++oo) {
        const float g  = sigmoid_f(GG[e][4*h + oo]);
        const float uo = accu[oo] * SQRT3;
        XV[e][(4*h+oo)*3+0] = fmaf(uo, ux, accv[oo*3+0]) * g;
        XV[e][(4*h+oo)*3+1] = fmaf(uo, uy, accv[oo*3+1]) * g;
        XV[e][(4*h+oo)*3+2] = fmaf(uo, uz, accv[oo*3+2]) * g;
    }
    __syncthreads();

    // ---- phase 2 (E2 = 80 rows) + staged coalesced message write ----
    edge_phase<64,16>(e, h, ux, uy, uz, XS, XV, W2s, B2, W2v, acc, accu, accv);
    __syncthreads();
    if (h == 3) {
#pragma unroll
        for (int u = 0; u < 16; ++u) GG[e][u] = acc[4+u];
    }
    {
        const int ns = (h == 3) ? 4 : 20;
        for (int u = 0; u < ns; ++u) XS[e][20*h + u] = gelu_f(acc[u]);
    }
    __syncthreads();
#pragma unroll
    for (int oo = 0; oo < 4; ++oo) {
        const float g  = sigmoid_f(GG[e][4*h + oo]);
        const float uo = accu[oo] * SQRT3;
        XV[e][(4*h+oo)*3+0] = fmaf(uo, ux, accv[oo*3+0]) * g;
        XV[e][(4*h+oo)*3+1] = fmaf(uo, uy, accv[oo*3+1]) * g;
        XV[e][(4*h+oo)*3+2] = fmaf(uo, uz, accv[oo*3+2]) * g;
    }
    __syncthreads();
    for (int idx = tid; idx < 64*115; idx += 256) {
        const int e2 = idx / 115, f = idx - e2*115;
        float vv;
        if (f < 64)       vv = XS[e2][f];
        else if (f < 112) vv = XV[e2][f-64];
        else              vv = UU[e2][f-112];
        msg[(size_t)(e0+e2)*116 + f] = vv;
    }
}

// ---------------- gather: CSR segment-mean -> y ----------------
__global__ __launch_bounds__(128)
void segnn_gather_kernel(const float* __restrict__ msg, const int* __restrict__ off,
                         const int* __restrict__ elist,
                         float* __restrict__ y_s, float* __restrict__ y_v) {
    const int n = blockIdx.x, f = threadIdx.x;
    const int o0 = off[n], o1 = off[n+1];
    const int deg = o1 - o0;
    float acc = 0.0f;
    for (int p = o0; p < o1; ++p) {
        const int eid = elist[p];
        if (f < 115) acc += msg[(size_t)eid*116 + f];
    }
    const float inv = NORMI / (float)(deg > 0 ? deg : 1);
    if (f < 64)        y_s[(size_t)n*65 + f] = acc * inv;
    else if (f < 112)  y_v[(size_t)n*51 + (f-64)] = acc * inv;
    else if (f < 115)  y_v[(size_t)n*51 + 48 + (f-112)] = SQRT3 * acc * inv;
    else if (f == 115) y_s[(size_t)n*65 + 64] = deg ? NORMI : 0.0f;
}

// ---------------- node TP-gate block: GEMM with on-the-fly X in LDS ----------------
// 8 nodes/block, 512 threads (8 waves), grid 512 (2 blocks/CU).
// ss phase:  C[8 x 80]  = X[8 x 4432]  * W[4432 x 80]
// vec phase: Cv[24 x 16] = Xv[24 x 2128] * Wv[2128 x 16]   (rows = (n,d))
__global__ __launch_bounds__(512, 4)
void segnn_node_kernel(const float* __restrict__ in_s, const float* __restrict__ in_v,
                       const float* __restrict__ y_s, const float* __restrict__ y_v,
                       const float* __restrict__ W,  const float* __restrict__ B,
                       const float* __restrict__ Wv,
                       float* __restrict__ out_s, float* __restrict__ out_v) {
    __shared__ __align__(16) float xsL[8*65];
    __shared__ __align__(16) float ysL[8*65];
    __shared__ __align__(16) float xvL[8*49];
    __shared__ __align__(16) float yvL[8*51];
    __shared__ __align__(16) float Xa[2][3072];       // K-tile arena (dbuf): ss uses 1024, vec 3072
    __shared__ __align__(16) float red[8][16][40];    // cross-wave reduction (vec reuses flat)
    __shared__ float finGG[8*16];                     // gate pre-activations

    const int tid  = threadIdx.x;
    const int lane = tid & 63;
    const int wv   = tid >> 6;            // wave 0..7
    const int nb0  = blockIdx.x * 8;

    // ---- stage per-node inputs ----
    for (int idx = tid; idx < 8*64; idx += 512) { const int n = idx >> 6, m = idx & 63; xsL[n*65+m] = in_s[(size_t)(nb0+n)*64 + m]; }
    for (int idx = tid; idx < 8*65; idx += 512) { const int n = idx / 65, k = idx - n*65; ysL[n*65+k] = y_s[(size_t)(nb0+n)*65 + k]; }
    for (int idx = tid; idx < 8*48; idx += 512) { const int n = idx / 48, m = idx - n*48; xvL[n*49+m] = in_v[(size_t)(nb0+n)*48 + m]; }
    for (int idx = tid; idx < 8*51; idx += 512) { const int n = idx / 51, m = idx - n*51; yvL[n*51+m] = y_v[(size_t)(nb0+n)*51 + m]; }
    __syncthreads();

    // ================= ss GEMM =================
    {
        const int cs = tid & 15;          // colslot: cols {cs, cs+16, cs+32, cs+48, cs+64}
        const int rowgrp = tid >> 4;      // 0..31, rows rowgrp + 32*v within tile

        float acc[8][5];
#pragma unroll
        for (int n = 0; n < 8; ++n)
#pragma unroll
            for (int c = 0; c < 5; ++c) acc[n][c] = 0.0f;

        // X generator for one 128-row tile
        auto genS = [&](int t, int b) {
            const int base = t * 128;
#pragma unroll
            for (int ii = 0; ii < 2; ++ii) {
                const int idx = tid + ii*512;
                const int rl = idx >> 3, n = idx & 7;
                const int r = base + rl;
                float val = 0.0f;
                if (r < 4160) {
                    const int m = r / 65, k = r - m*65;
                    val = xsL[n*65+m] * ysL[n*65+k];
                } else if (r < 4432) {
                    const int q = r - 4160;
                    const int m = q / 17, k = q - m*17;
                    val = (xvL[n*49+m*3+0]*yvL[n*51+k*3+0] +
                           xvL[n*49+m*3+1]*yvL[n*51+k*3+1] +
                           xvL[n*49+m*3+2]*yvL[n*51+k*3+2]) * ISQRT3;
                }
                Xa[b][idx] = val;
            }
        };

        genS(0, 0);
        __syncthreads();
        for (int t = 0; t < 35; ++t) {
            if (t + 1 < 35) genS(t + 1, (t + 1) & 1);
            const int base = t * 128;
            const float* Xb = &Xa[t & 1][0];
#pragma unroll
            for (int vv = 0; vv < 4; ++vv) {
                const int rl = rowgrp + 32*vv;
                const int r  = base + rl;
                const int wr = r < 4431 ? r : 4431;   // clamp (X is 0 beyond K)
                const float* wp = W + (size_t)wr * 80 + cs;
                const float w0 = wp[0], w1 = wp[16], w2 = wp[32], w3 = wp[48], w4_ = wp[64];
                const float4 xq0 = *reinterpret_cast<const float4*>(&Xb[rl*8]);
                const float4 xq1 = *reinterpret_cast<const float4*>(&Xb[rl*8+4]);
                const float xn[8] = { xq0.x, xq0.y, xq0.z, xq0.w, xq1.x, xq1.y, xq1.z, xq1.w };
#pragma unroll
                for (int n = 0; n < 8; ++n) {
                    acc[n][0] = fmaf(xn[n], w0,  acc[n][0]);
                    acc[n][1] = fmaf(xn[n], w1,  acc[n][1]);
                    acc[n][2] = fmaf(xn[n], w2,  acc[n][2]);
                    acc[n][3] = fmaf(xn[n], w3,  acc[n][3]);
                    acc[n][4] = fmaf(xn[n], w4_, acc[n][4]);
                }
            }
            __syncthreads();
        }

        // in-wave reduce over 4 rowgrps, then cross-wave via LDS
#pragma unroll
        for (int n = 0; n < 8; ++n)
#pragma unroll
            for (int c = 0; c < 5; ++c) {
                float a = acc[n][c];
                a += __shfl_xor(a, 16);
                a += __shfl_xor(a, 32);
                if (lane < 16) red[wv][lane][n*5+c] = a;
            }
        __syncthreads();
        for (int idx = tid; idx < 8*80; idx += 512) {
            const int n = idx / 80, col = idx - n*80;
            const int cs2 = col & 15, ci2 = col >> 4;
            float s = B[col];
#pragma unroll
            for (int w = 0; w < 8; ++w) s += red[w][cs2][n*5+ci2];
            if (col < 64) out_s[(size_t)(nb0+n)*64 + col] = gelu_f(s);
            else          finGG[n*16 + (col-64)] = s;
        }
    }

    // ================= vec GEMM =================
    {
        const int j4 = tid & 3;           // cols 4*j4 .. 4*j4+3
        const int ngrp = (tid >> 2) & 1;  // arows 12*ngrp .. +11
        const int rg = tid >> 3;          // 0..63, rows rg + 64*v within tile

        float av[12][4];
#pragma unroll
        for (int a = 0; a < 12; ++a)
#pragma unroll
            for (int c = 0; c < 4; ++c) av[a][c] = 0.0f;

        auto genV = [&](int t, int b) {
            const int base = t * 128;
#pragma unroll
            for (int ii = 0; ii < 6; ++ii) {
                const int idx = tid + ii*512;
                const int rl = idx / 24, ar = idx - rl*24;
                const int n = ar / 3, d = ar - n*3;
                const int r = base + rl;
                float val = 0.0f;
                if (r < 1088) {
                    const int m = r / 17, k = r - m*17;
                    val = xsL[n*65+m] * yvL[n*51+k*3+d];
                } else if (r < 2128) {
                    const int q = r - 1088;
                    const int m = q / 65, k = q - m*65;
                    val = xvL[n*49+m*3+d] * ysL[n*65+k];
                }
                Xa[b][idx] = val;
            }
        };

        genV(0, 0);
        __syncthreads();
        for (int t = 0; t < 17; ++t) {
            if (t + 1 < 17) genV(t + 1, (t + 1) & 1);
            const int base = t * 128;
            const float* Xb = &Xa[t & 1][0];
#pragma unroll
            for (int vv = 0; vv < 2; ++vv) {
                const int rl = rg + 64*vv;
                const int r  = base + rl;
                const int wr = r < 2127 ? r : 2127;
                const float4 w4 = *reinterpret_cast<const float4*>(&Wv[(size_t)wr*16 + 4*j4]);
                const float4 xq0 = *reinterpret_cast<const float4*>(&Xb[rl*24 + 12*ngrp]);
                const float4 xq1 = *reinterpret_cast<const float4*>(&Xb[rl*24 + 12*ngrp + 4]);
                const float4 xq2 = *reinterpret_cast<const float4*>(&Xb[rl*24 + 12*ngrp + 8]);
                const float xr[12] = { xq0.x,xq0.y,xq0.z,xq0.w, xq1.x,xq1.y,xq1.z,xq1.w, xq2.x,xq2.y,xq2.z,xq2.w };
#pragma unroll
                for (int a = 0; a < 12; ++a) {
                    av[a][0] = fmaf(xr[a], w4.x, av[a][0]);
                    av[a][1] = fmaf(xr[a], w4.y, av[a][1]);
                    av[a][2] = fmaf(xr[a], w4.z, av[a][2]);
                    av[a][3] = fmaf(xr[a], w4.w, av[a][3]);
                }
            }
            __syncthreads();
        }

        // reduce over 8 in-wave rowgroups, then 8 waves
        float* redf = &red[0][0][0];
#pragma unroll
        for (int a = 0; a < 12; ++a)
#pragma unroll
            for (int c = 0; c < 4; ++c) {
                float x = av[a][c];
                x += __shfl_xor(x, 8);
                x += __shfl_xor(x, 16);
                x += __shfl_xor(x, 32);
                if (lane < 8) redf[wv*384 + lane*48 + a*4 + c] = x;
            }
        __syncthreads();
        for (int idx = tid; idx < 24*16; idx += 512) {
            const int ar = idx >> 4, j = idx & 15;
            const int n = ar / 3, d = ar - n*3;
            const int ng2 = ar / 12, a2 = ar - 12*ng2;
            const int jj4 = j >> 2, c2 = j & 3;
            float s = 0.0f;
#pragma unroll
            for (int w = 0; w < 8; ++w) s += redf[w*384 + (jj4 + 4*ng2)*48 + a2*4 + c2];
            out_v[(size_t)(nb0+n)*48 + j*3 + d] = s * sigmoid_f(finGG[n*16 + j]);
        }
    }
}

// ---------------- per-step final Linear ----------------
__global__ __launch_bounds__(256)
void segnn_linear_kernel(const float* __restrict__ in_s, const float* __restrict__ in_v,
                         const float* __restrict__ lws, const float* __restrict__ lb,
                         const float* __restrict__ lwv,
                         float* __restrict__ out_s, float* __restrict__ out_v,
                         float* __restrict__ out_cat) {
    const int idx = blockIdx.x * 256 + threadIdx.x;
    if (idx >= NND * 112) return;
    const int nidx = idx / 112, f = idx - nidx * 112;
    if (f < 48) {
        const int k = f / 3, d = f - 3*k;
        const float* vp = in_v + (size_t)nidx * 48 + d;
        float acc = 0.0f;
#pragma unroll
        for (int m = 0; m < 16; ++m) acc = fmaf(vp[m*3], lwv[m*16 + k], acc);
        if (out_cat) out_cat[(size_t)nidx*112 + f] = acc;
        else         out_v[(size_t)nidx*48 + f] = acc;
    } else {
        const int o = f - 48;
        const float* sp = in_s + (size_t)nidx * 64;
        float acc = lb[o];
#pragma unroll
        for (int m = 0; m < 64; ++m) acc = fmaf(sp[m], lws[m*64 + o], acc);
        if (out_cat) out_cat[(size_t)nidx*112 + f] = acc;
        else         out_s[(size_t)nidx*64 + o] = acc;
    }
}

// ---------------- host launcher ----------------
extern "C" void kernel_launch(void* const* d_in, const int* in_sizes, int n_in,
                              void* d_out, int out_size, void* d_ws, size_t ws_size,
                              hipStream_t stream) {
    const float* in_s  = (const float*)d_in[0];
    const float* in_v  = (const float*)d_in[1];
    const int*   snd   = (const int*)  d_in[2];
    const int*   rcv   = (const int*)  d_in[3];
    const float* e1_ws = (const float*)d_in[4];
    const float* e1_b  = (const float*)d_in[5];
    const float* e1_wv = (const float*)d_in[6];
    const float* e2_ws = (const float*)d_in[7];
    const float* e2_b  = (const float*)d_in[8];
    const float* e2_wv = (const float*)d_in[9];
    const float* n_ws  = (const float*)d_in[10];
    const float* n_b   = (const float*)d_in[11];
    const float* n_wv  = (const float*)d_in[12];
    const float* l_ws  = (const float*)d_in[13];
    const float* l_b   = (const float*)d_in[14];
    const float* l_wv  = (const float*)d_in[15];

    float* ws    = (float*)d_ws;
    float* cur_s = ws;                           // N*64   = 262144
    float* cur_v = cur_s + 262144;               // N*48   = 196608
    float* nxt_s = cur_v + 196608;               // N*64
    float* nxt_v = nxt_s + 262144;               // N*48
    float* y_s   = nxt_v + 196608;               // N*65   = 266240
    float* y_v   = y_s + 266240;                 // N*51   = 208896
    float* msg   = y_v + 208896;                 // E*116  = 3801088
    int*   deg    = (int*)(msg + 3801088);       // N
    int*   cursor = deg + 4096;                  // N
    int*   off    = cursor + 4096;               // N+1
    int*   elist  = off + 4097;                  // E

    hipMemsetAsync(deg, 0, (size_t)8192 * sizeof(int), stream);
    hipMemcpyAsync(cur_s, in_s, (size_t)262144 * sizeof(float), hipMemcpyDeviceToDevice, stream);
    hipMemcpyAsync(cur_v, in_v, (size_t)196608 * sizeof(float), hipMemcpyDeviceToDevice, stream);
    segnn_deg_kernel<<<EDG/256, 256, 0, stream>>>(rcv, deg);
    segnn_scan_kernel<<<1, 1024, 0, stream>>>(deg, off);
    segnn_scatter_kernel<<<EDG/256, 256, 0, stream>>>(rcv, off, cursor, elist);

    for (int step = 0; step < 3; ++step) {
        segnn_edge_fused<<<EDG/64, 256, 0, stream>>>(cur_s, cur_v, snd, rcv,
            e1_ws + (size_t)step*160*80, e1_b + step*80, e1_wv + (size_t)step*160*16,
            e2_ws + (size_t)(step*2+0)*80*80, e2_b + (step*2+0)*80, e2_wv + (size_t)(step*2+0)*80*16,
            e2_ws + (size_t)(step*2+1)*80*80, e2_b + (step*2+1)*80, e2_wv + (size_t)(step*2+1)*80*16,
            msg);
        segnn_gather_kernel<<<NND, 128, 0, stream>>>(msg, off, elist, y_s, y_v);

        segnn_node_kernel<<<NND/8, 512, 0, stream>>>(cur_s, cur_v, y_s, y_v,
            n_ws + (size_t)(step*3+0)*4432*80, n_b + (step*3+0)*80, n_wv + (size_t)(step*3+0)*2128*16,
            nxt_s, nxt_v);
        segnn_node_kernel<<<NND/8, 512, 0, stream>>>(nxt_s, nxt_v, y_s, y_v,
            n_ws + (size_t)(step*3+1)*4432*80, n_b + (step*3+1)*80, n_wv + (size_t)(step*3+1)*2128*16,
            cur_s, cur_v);
        segnn_node_kernel<<<NND/8, 512, 0, stream>>>(cur_s, cur_v, y_s, y_v,
            n_ws + (size_t)(step*3+2)*4432*80, n_b + (step*3+2)*80, n_wv + (size_t)(step*3+2)*2128*16,
            nxt_s, nxt_v);

        segnn_linear_kernel<<<(NND*112 + 255)/256, 256, 0, stream>>>(nxt_s, nxt_v,
            l_ws + (size_t)step*64*64, l_b + step*64, l_wv + (size_t)step*16*16,
            cur_s, cur_v, (step == 2) ? (float*)d_out : nullptr);
    }
}

// Round 5
// 1180.635 us; speedup vs baseline: 2.6420x; 1.0655x over previous
//
#include <hip/hip_runtime.h>
#include <math.h>

// ---------------- problem constants ----------------
constexpr int NND = 4096;     // nodes
constexpr int EDG = 32768;    // edges
constexpr float SQRT3  = 1.7320508075688772f;
constexpr float ISQRT3 = 0.5773502691896258f;
constexpr float NORMI  = 1.0f / 32767.0f;   // 1/(E-1)

__device__ __forceinline__ float gelu_f(float x) {
    float x3 = x * x * x;
    return 0.5f * x * (1.0f + tanhf(0.7978845608028654f * (x + 0.044715f * x3)));
}
__device__ __forceinline__ float sigmoid_f(float x) {
    return 1.0f / (1.0f + expf(-x));
}

// acc[4*NO4] += x * w[0..4*NO4)
template<int NO4>
__device__ __forceinline__ void rank1(float* acc, float x, const float* w) {
#pragma unroll
    for (int u = 0; u < NO4; ++u) {
        const float4 q = *reinterpret_cast<const float4*>(w + 4 * u);
        acc[4*u+0] = fmaf(x, q.x, acc[4*u+0]);
        acc[4*u+1] = fmaf(x, q.y, acc[4*u+1]);
        acc[4*u+2] = fmaf(x, q.z, acc[4*u+2]);
        acc[4*u+3] = fmaf(x, q.w, acc[4*u+3]);
    }
}

// ---------------- CSR construction (once per launch) ----------------
__global__ __launch_bounds__(256)
void segnn_deg_kernel(const int* __restrict__ rcv, int* __restrict__ deg) {
    const int e = blockIdx.x * 256 + threadIdx.x;
    if (e < EDG) atomicAdd(deg + rcv[e], 1);
}

__global__ __launch_bounds__(1024)
void segnn_scan_kernel(const int* __restrict__ deg, int* __restrict__ off) {
    __shared__ int tots[1024];
    const int t = threadIdx.x;
    const int v0 = deg[4*t], v1 = deg[4*t+1], v2 = deg[4*t+2], v3 = deg[4*t+3];
    const int p1 = v0, p2 = p1 + v1, p3 = p2 + v2, p4 = p3 + v3;
    tots[t] = p4;
    __syncthreads();
    for (int d = 1; d < 1024; d <<= 1) {
        const int add = (t >= d) ? tots[t - d] : 0;
        __syncthreads();
        tots[t] += add;
        __syncthreads();
    }
    const int excl = t ? tots[t-1] : 0;
    off[4*t+0] = excl;
    off[4*t+1] = excl + p1;
    off[4*t+2] = excl + p2;
    off[4*t+3] = excl + p3;
    if (t == 1023) off[4096] = tots[1023];
}

__global__ __launch_bounds__(256)
void segnn_scatter_kernel(const int* __restrict__ rcv, const int* __restrict__ off,
                          int* __restrict__ cursor, int* __restrict__ elist) {
    const int e = blockIdx.x * 256 + threadIdx.x;
    if (e < EDG) {
        const int j = rcv[e];
        const int p = atomicAdd(cursor + j, 1);
        elist[off[j] + p] = e;
    }
}

// ---------------- fused edge pipeline as GEMM (16 edges/block) ----------------
// Pass A: C[16e][96] = XT[KA][16e]^T * [Ws | Wv-scalar-rows] ; KA = NSX (scalar) + NVX (dot rows)
// Pass B: Cv[16e][16o x 3d] = X2T[3*NVX][16e]^T * Wv-vector-rows (per component d)
template<int NSX, int NVX>
__device__ __forceinline__ void edge_gemm_phase(
    const int tid,
    const float* __restrict__ Ws, const float* __restrict__ Bs,
    const float* __restrict__ Wv,
    const float (*XT)[20], const float (*X2T)[20],
    float (*red)[16][8][6], float (*Cbuf)[96], float (*Cv)[48])
{
    const int cs   = tid & 15;          // column slot
    const int rgl  = (tid >> 4) & 3;    // in-wave K sub-chunk
    const int wvw  = tid >> 6;          // wave 0..3
    const int eg   = wvw & 1;           // edge half (8 edges)
    const int kh   = wvw >> 1;          // K half
    const int lane = tid & 63;
    constexpr int KA = NSX + NVX;
    constexpr int CH = KA / 8;

    // ---- pass A ----
    {
        float acc[8][6];
#pragma unroll
        for (int j = 0; j < 8; ++j)
#pragma unroll
            for (int c = 0; c < 6; ++c) acc[j][c] = 0.0f;
        const int r0 = (kh*4 + rgl) * CH;
#pragma unroll 2
        for (int rr = 0; rr < CH; ++rr) {
            const int r = r0 + rr;
            const float* wp = Ws + r*80 + cs;
            const float w0 = wp[0], w1 = wp[16], w2 = wp[32], w3 = wp[48], w4 = wp[64];
            const float w5 = (r < NSX) ? Wv[r*16 + cs] : 0.0f;   // t-path: scalar rows only
            const float4 xa = *reinterpret_cast<const float4*>(&XT[r][8*eg]);
            const float4 xb = *reinterpret_cast<const float4*>(&XT[r][8*eg+4]);
            const float xe[8] = { xa.x,xa.y,xa.z,xa.w, xb.x,xb.y,xb.z,xb.w };
#pragma unroll
            for (int j = 0; j < 8; ++j) {
                acc[j][0] = fmaf(xe[j], w0, acc[j][0]);
                acc[j][1] = fmaf(xe[j], w1, acc[j][1]);
                acc[j][2] = fmaf(xe[j], w2, acc[j][2]);
                acc[j][3] = fmaf(xe[j], w3, acc[j][3]);
                acc[j][4] = fmaf(xe[j], w4, acc[j][4]);
                acc[j][5] = fmaf(xe[j], w5, acc[j][5]);
            }
        }
#pragma unroll
        for (int j = 0; j < 8; ++j)
#pragma unroll
            for (int c = 0; c < 6; ++c) {
                float a = acc[j][c];
                a += __shfl_xor(a, 16);
                a += __shfl_xor(a, 32);
                acc[j][c] = a;
            }
        if (lane < 16) {
#pragma unroll
            for (int j = 0; j < 8; ++j)
#pragma unroll
                for (int c = 0; c < 6; ++c) red[wvw][lane][j][c] = acc[j][c];
        }
    }
    __syncthreads();
    for (int idx = tid; idx < 16*96; idx += 256) {
        const int e = idx / 96, col = idx - e*96;
        const int eg2 = e >> 3, j = e & 7;
        const int cs2 = col & 15, ci = col >> 4;
        float s = red[eg2][cs2][j][ci] + red[2+eg2][cs2][j][ci];
        if (col < 80) s += Bs[col];
        Cbuf[e][col] = s;
    }
    __syncthreads();

    // ---- pass B (identity-path vector outputs) ----
    {
        constexpr int CHB = NVX / 8;
        float av[8][3];
#pragma unroll
        for (int j = 0; j < 8; ++j) { av[j][0]=0.0f; av[j][1]=0.0f; av[j][2]=0.0f; }
        const int m0 = (kh*4 + rgl) * CHB;
#pragma unroll
        for (int mm = 0; mm < CHB; ++mm) {
            const int m = m0 + mm;
            const float w = Wv[(NSX + m)*16 + cs];
#pragma unroll
            for (int d = 0; d < 3; ++d) {
                const float4 xa = *reinterpret_cast<const float4*>(&X2T[d*NVX + m][8*eg]);
                const float4 xb = *reinterpret_cast<const float4*>(&X2T[d*NVX + m][8*eg+4]);
                const float xe[8] = { xa.x,xa.y,xa.z,xa.w, xb.x,xb.y,xb.z,xb.w };
#pragma unroll
                for (int j = 0; j < 8; ++j) av[j][d] = fmaf(xe[j], w, av[j][d]);
            }
        }
#pragma unroll
        for (int j = 0; j < 8; ++j)
#pragma unroll
            for (int d = 0; d < 3; ++d) {
                float a = av[j][d];
                a += __shfl_xor(a, 16);
                a += __shfl_xor(a, 32);
                av[j][d] = a;
            }
        if (lane < 16) {
#pragma unroll
            for (int j = 0; j < 8; ++j)
#pragma unroll
                for (int d = 0; d < 3; ++d) red[wvw][lane][j][d] = av[j][d];
        }
    }
    __syncthreads();
    for (int idx = tid; idx < 16*48; idx += 256) {
        const int e = idx / 48, q = idx - e*48;
        const int o = q / 3, d = q - 3*o;
        const int eg2 = e >> 3, j = e & 7;
        Cv[e][q] = red[eg2][o][j][d] + red[2+eg2][o][j][d];
    }
    __syncthreads();
}

__global__ __launch_bounds__(256, 3)
void segnn_edge_fused(const float* __restrict__ cs, const float* __restrict__ cv,
                      const int* __restrict__ snd, const int* __restrict__ rcv,
                      const float* __restrict__ W0s, const float* __restrict__ B0, const float* __restrict__ W0v,
                      const float* __restrict__ W1s, const float* __restrict__ B1, const float* __restrict__ W1v,
                      const float* __restrict__ W2s, const float* __restrict__ B2, const float* __restrict__ W2v,
                      float* __restrict__ msg) {
    __shared__ __align__(16) float XT[160][20];    // pass-A rows (transposed): scalar | dot
    __shared__ __align__(16) float X2T[96][20];    // pass-B rows: (d*NVX+m) -> v_m[d]
    __shared__ float red[4][16][8][6];
    __shared__ float Cbuf[16][96];
    __shared__ float Cv[16][48];
    __shared__ float uu[16][4];
    __shared__ int   nd[16][2];

    const int tid = threadIdx.x;
    const int e0  = blockIdx.x * 16;

    if (tid < 16) { nd[tid][0] = snd[e0+tid]; nd[tid][1] = rcv[e0+tid]; }
    __syncthreads();
    // scalar rows 0..127 = [s_i | s_j]
    for (int idx = tid; idx < 16*128; idx += 256) {
        const int e = idx >> 7, m = idx & 127;
        const int node = nd[e][m >> 6];
        XT[m][e] = cs[(size_t)node*64 + (m & 63)];
    }
    // X2 rows: (d*32 + part*16 + m) = v-component features
    for (int idx = tid; idx < 16*96; idx += 256) {
        const int e = idx / 96, q = idx - e*96;
        const int part = q / 48, md = q - part*48;
        const int m = md / 3, d = md - m*3;
        const int node = nd[e][part];
        X2T[d*32 + part*16 + m][e] = cv[(size_t)node*48 + m*3 + d];
    }
    __syncthreads();
    if (tid < 16) {
        const float rx = X2T[0][tid]  - X2T[16][tid];
        const float ry = X2T[32][tid] - X2T[48][tid];
        const float rz = X2T[64][tid] - X2T[80][tid];
        const float rinv = 1.0f / fmaxf(sqrtf(rx*rx+ry*ry+rz*rz), 1e-9f);
        uu[tid][0] = rx*rinv; uu[tid][1] = ry*rinv; uu[tid][2] = rz*rinv;
    }
    __syncthreads();
    // dot rows 128..159: v_m . u
    for (int idx = tid; idx < 16*32; idx += 256) {
        const int e = idx >> 5, mm = idx & 31;
        XT[128 + mm][e] = X2T[mm][e]*uu[e][0] + X2T[32+mm][e]*uu[e][1] + X2T[64+mm][e]*uu[e][2];
    }
    __syncthreads();

    // ---- phase 0 ----
    edge_gemm_phase<128,32>(tid, W0s, B0, W0v, XT, X2T, red, Cbuf, Cv);
    // activation -> next XT (64 scalar + 16 dot) and X2T (48 rows)
    for (int idx = tid; idx < 16*64; idx += 256) {
        const int e = idx >> 6, m = idx & 63;
        XT[m][e] = gelu_f(Cbuf[e][m]);
    }
    for (int idx = tid; idx < 16*16; idx += 256) {
        const int e = idx >> 4, o = idx & 15;
        const float g = sigmoid_f(Cbuf[e][64+o]);
        const float t = Cbuf[e][80+o] * SQRT3;
        float p = 0.0f;
#pragma unroll
        for (int d = 0; d < 3; ++d) {
            const float vd = fmaf(t, uu[e][d], Cv[e][o*3+d]) * g;
            X2T[d*16 + o][e] = vd;
            p = fmaf(vd, uu[e][d], p);
        }
        XT[64 + o][e] = p;
    }
    __syncthreads();

    // ---- phase 1 ----
    edge_gemm_phase<64,16>(tid, W1s, B1, W1v, XT, X2T, red, Cbuf, Cv);
    for (int idx = tid; idx < 16*64; idx += 256) {
        const int e = idx >> 6, m = idx & 63;
        XT[m][e] = gelu_f(Cbuf[e][m]);
    }
    for (int idx = tid; idx < 16*16; idx += 256) {
        const int e = idx >> 4, o = idx & 15;
        const float g = sigmoid_f(Cbuf[e][64+o]);
        const float t = Cbuf[e][80+o] * SQRT3;
        float p = 0.0f;
#pragma unroll
        for (int d = 0; d < 3; ++d) {
            const float vd = fmaf(t, uu[e][d], Cv[e][o*3+d]) * g;
            X2T[d*16 + o][e] = vd;
            p = fmaf(vd, uu[e][d], p);
        }
        XT[64 + o][e] = p;
    }
    __syncthreads();

    // ---- phase 2 + coalesced message write ----
    edge_gemm_phase<64,16>(tid, W2s, B2, W2v, XT, X2T, red, Cbuf, Cv);
    for (int idx = tid; idx < 16*115; idx += 256) {
        const int e = idx / 115, f = idx - e*115;
        float vv;
        if (f < 64) {
            vv = gelu_f(Cbuf[e][f]);
        } else if (f < 112) {
            const int q = f - 64, o = q / 3, d = q - 3*o;
            const float g = sigmoid_f(Cbuf[e][64+o]);
            vv = fmaf(Cbuf[e][80+o] * SQRT3, uu[e][d], Cv[e][q]) * g;
        } else {
            vv = uu[e][f-112];
        }
        msg[(size_t)(e0+e)*116 + f] = vv;
    }
}

// ---------------- gather: CSR segment-mean -> y ----------------
__global__ __launch_bounds__(128)
void segnn_gather_kernel(const float* __restrict__ msg, const int* __restrict__ off,
                         const int* __restrict__ elist,
                         float* __restrict__ y_s, float* __restrict__ y_v) {
    const int n = blockIdx.x, f = threadIdx.x;
    const int o0 = off[n], o1 = off[n+1];
    const int deg = o1 - o0;
    float acc = 0.0f;
    for (int p = o0; p < o1; ++p) {
        const int eid = elist[p];
        if (f < 115) acc += msg[(size_t)eid*116 + f];
    }
    const float inv = NORMI / (float)(deg > 0 ? deg : 1);
    if (f < 64)        y_s[(size_t)n*65 + f] = acc * inv;
    else if (f < 112)  y_v[(size_t)n*51 + (f-64)] = acc * inv;
    else if (f < 115)  y_v[(size_t)n*51 + 48 + (f-112)] = SQRT3 * acc * inv;
    else if (f == 115) y_s[(size_t)n*65 + 64] = deg ? NORMI : 0.0f;
}

// ---------------- node TP-gate block: GEMM with on-the-fly X in LDS ----------------
__global__ __launch_bounds__(512, 4)
void segnn_node_kernel(const float* __restrict__ in_s, const float* __restrict__ in_v,
                       const float* __restrict__ y_s, const float* __restrict__ y_v,
                       const float* __restrict__ W,  const float* __restrict__ B,
                       const float* __restrict__ Wv,
                       float* __restrict__ out_s, float* __restrict__ out_v) {
    __shared__ __align__(16) float xsL[8*65];
    __shared__ __align__(16) float ysL[8*65];
    __shared__ __align__(16) float xvL[8*49];
    __shared__ __align__(16) float yvL[8*51];
    __shared__ __align__(16) float Xa[2][3072];
    __shared__ __align__(16) float red[8][16][40];
    __shared__ float finGG[8*16];

    const int tid  = threadIdx.x;
    const int lane = tid & 63;
    const int wv   = tid >> 6;
    const int nb0  = blockIdx.x * 8;

    for (int idx = tid; idx < 8*64; idx += 512) { const int n = idx >> 6, m = idx & 63; xsL[n*65+m] = in_s[(size_t)(nb0+n)*64 + m]; }
    for (int idx = tid; idx < 8*65; idx += 512) { const int n = idx / 65, k = idx - n*65; ysL[n*65+k] = y_s[(size_t)(nb0+n)*65 + k]; }
    for (int idx = tid; idx < 8*48; idx += 512) { const int n = idx / 48, m = idx - n*48; xvL[n*49+m] = in_v[(size_t)(nb0+n)*48 + m]; }
    for (int idx = tid; idx < 8*51; idx += 512) { const int n = idx / 51, m = idx - n*51; yvL[n*51+m] = y_v[(size_t)(nb0+n)*51 + m]; }
    __syncthreads();

    // ================= ss GEMM =================
    {
        const int cs = tid & 15;
        const int rowgrp = tid >> 4;

        float acc[8][5];
#pragma unroll
        for (int n = 0; n < 8; ++n)
#pragma unroll
            for (int c = 0; c < 5; ++c) acc[n][c] = 0.0f;

        auto genS = [&](int t, int b) {
            const int base = t * 128;
#pragma unroll
            for (int ii = 0; ii < 2; ++ii) {
                const int idx = tid + ii*512;
                const int rl = idx >> 3, n = idx & 7;
                const int r = base + rl;
                float val = 0.0f;
                if (r < 4160) {
                    const int m = r / 65, k = r - m*65;
                    val = xsL[n*65+m] * ysL[n*65+k];
                } else if (r < 4432) {
                    const int q = r - 4160;
                    const int m = q / 17, k = q - m*17;
                    val = (xvL[n*49+m*3+0]*yvL[n*51+k*3+0] +
                           xvL[n*49+m*3+1]*yvL[n*51+k*3+1] +
                           xvL[n*49+m*3+2]*yvL[n*51+k*3+2]) * ISQRT3;
                }
                Xa[b][idx] = val;
            }
        };

        genS(0, 0);
        __syncthreads();
        for (int t = 0; t < 35; ++t) {
            if (t + 1 < 35) genS(t + 1, (t + 1) & 1);
            const int base = t * 128;
            const float* Xb = &Xa[t & 1][0];
#pragma unroll
            for (int vv = 0; vv < 4; ++vv) {
                const int rl = rowgrp + 32*vv;
                const int r  = base + rl;
                const int wr = r < 4431 ? r : 4431;
                const float* wp = W + (size_t)wr * 80 + cs;
                const float w0 = wp[0], w1 = wp[16], w2 = wp[32], w3 = wp[48], w4_ = wp[64];
                const float4 xq0 = *reinterpret_cast<const float4*>(&Xb[rl*8]);
                const float4 xq1 = *reinterpret_cast<const float4*>(&Xb[rl*8+4]);
                const float xn[8] = { xq0.x, xq0.y, xq0.z, xq0.w, xq1.x, xq1.y, xq1.z, xq1.w };
#pragma unroll
                for (int n = 0; n < 8; ++n) {
                    acc[n][0] = fmaf(xn[n], w0,  acc[n][0]);
                    acc[n][1] = fmaf(xn[n], w1,  acc[n][1]);
                    acc[n][2] = fmaf(xn[n], w2,  acc[n][2]);
                    acc[n][3] = fmaf(xn[n], w3,  acc[n][3]);
                    acc[n][4] = fmaf(xn[n], w4_, acc[n][4]);
                }
            }
            __syncthreads();
        }

#pragma unroll
        for (int n = 0; n < 8; ++n)
#pragma unroll
            for (int c = 0; c < 5; ++c) {
                float a = acc[n][c];
                a += __shfl_xor(a, 16);
                a += __shfl_xor(a, 32);
                if (lane < 16) red[wv][lane][n*5+c] = a;
            }
        __syncthreads();
        for (int idx = tid; idx < 8*80; idx += 512) {
            const int n = idx / 80, col = idx - n*80;
            const int cs2 = col & 15, ci2 = col >> 4;
            float s = B[col];
#pragma unroll
            for (int w = 0; w < 8; ++w) s += red[w][cs2][n*5+ci2];
            if (col < 64) out_s[(size_t)(nb0+n)*64 + col] = gelu_f(s);
            else          finGG[n*16 + (col-64)] = s;
        }
    }

    // ================= vec GEMM =================
    {
        const int j4 = tid & 3;
        const int ngrp = (tid >> 2) & 1;
        const int rg = tid >> 3;

        float av[12][4];
#pragma unroll
        for (int a = 0; a < 12; ++a)
#pragma unroll
            for (int c = 0; c < 4; ++c) av[a][c] = 0.0f;

        auto genV = [&](int t, int b) {
            const int base = t * 128;
#pragma unroll
            for (int ii = 0; ii < 6; ++ii) {
                const int idx = tid + ii*512;
                const int rl = idx / 24, ar = idx - rl*24;
                const int n = ar / 3, d = ar - n*3;
                const int r = base + rl;
                float val = 0.0f;
                if (r < 1088) {
                    const int m = r / 17, k = r - m*17;
                    val = xsL[n*65+m] * yvL[n*51+k*3+d];
                } else if (r < 2128) {
                    const int q = r - 1088;
                    const int m = q / 65, k = q - m*65;
                    val = xvL[n*49+m*3+d] * ysL[n*65+k];
                }
                Xa[b][idx] = val;
            }
        };

        genV(0, 0);
        __syncthreads();
        for (int t = 0; t < 17; ++t) {
            if (t + 1 < 17) genV(t + 1, (t + 1) & 1);
            const int base = t * 128;
            const float* Xb = &Xa[t & 1][0];
#pragma unroll
            for (int vv = 0; vv < 2; ++vv) {
                const int rl = rg + 64*vv;
                const int r  = base + rl;
                const int wr = r < 2127 ? r : 2127;
                const float4 w4 = *reinterpret_cast<const float4*>(&Wv[(size_t)wr*16 + 4*j4]);
                const float4 xq0 = *reinterpret_cast<const float4*>(&Xb[rl*24 + 12*ngrp]);
                const float4 xq1 = *reinterpret_cast<const float4*>(&Xb[rl*24 + 12*ngrp + 4]);
                const float4 xq2 = *reinterpret_cast<const float4*>(&Xb[rl*24 + 12*ngrp + 8]);
                const float xr[12] = { xq0.x,xq0.y,xq0.z,xq0.w, xq1.x,xq1.y,xq1.z,xq1.w, xq2.x,xq2.y,xq2.z,xq2.w };
#pragma unroll
                for (int a = 0; a < 12; ++a) {
                    av[a][0] = fmaf(xr[a], w4.x, av[a][0]);
                    av[a][1] = fmaf(xr[a], w4.y, av[a][1]);
                    av[a][2] = fmaf(xr[a], w4.z, av[a][2]);
                    av[a][3] = fmaf(xr[a], w4.w, av[a][3]);
                }
            }
            __syncthreads();
        }

        float* redf = &red[0][0][0];
#pragma unroll
        for (int a = 0; a < 12; ++a)
#pragma unroll
            for (int c = 0; c < 4; ++c) {
                float x = av[a][c];
                x += __shfl_xor(x, 8);
                x += __shfl_xor(x, 16);
                x += __shfl_xor(x, 32);
                if (lane < 8) redf[wv*384 + lane*48 + a*4 + c] = x;
            }
        __syncthreads();
        for (int idx = tid; idx < 24*16; idx += 512) {
            const int ar = idx >> 4, j = idx & 15;
            const int n = ar / 3, d = ar - n*3;
            const int ng2 = ar / 12, a2 = ar - 12*ng2;
            const int jj4 = j >> 2, c2 = j & 3;
            float s = 0.0f;
#pragma unroll
            for (int w = 0; w < 8; ++w) s += redf[w*384 + (jj4 + 4*ng2)*48 + a2*4 + c2];
            out_v[(size_t)(nb0+n)*48 + j*3 + d] = s * sigmoid_f(finGG[n*16 + j]);
        }
    }
}

// ---------------- per-step final Linear ----------------
__global__ __launch_bounds__(256)
void segnn_linear_kernel(const float* __restrict__ in_s, const float* __restrict__ in_v,
                         const float* __restrict__ lws, const float* __restrict__ lb,
                         const float* __restrict__ lwv,
                         float* __restrict__ out_s, float* __restrict__ out_v,
                         float* __restrict__ out_cat) {
    const int idx = blockIdx.x * 256 + threadIdx.x;
    if (idx >= NND * 112) return;
    const int nidx = idx / 112, f = idx - nidx * 112;
    if (f < 48) {
        const int k = f / 3, d = f - 3*k;
        const float* vp = in_v + (size_t)nidx * 48 + d;
        float acc = 0.0f;
#pragma unroll
        for (int m = 0; m < 16; ++m) acc = fmaf(vp[m*3], lwv[m*16 + k], acc);
        if (out_cat) out_cat[(size_t)nidx*112 + f] = acc;
        else         out_v[(size_t)nidx*48 + f] = acc;
    } else {
        const int o = f - 48;
        const float* sp = in_s + (size_t)nidx * 64;
        float acc = lb[o];
#pragma unroll
        for (int m = 0; m < 64; ++m) acc = fmaf(sp[m], lws[m*64 + o], acc);
        if (out_cat) out_cat[(size_t)nidx*112 + f] = acc;
        else         out_s[(size_t)nidx*64 + o] = acc;
    }
}

// ---------------- host launcher ----------------
extern "C" void kernel_launch(void* const* d_in, const int* in_sizes, int n_in,
                              void* d_out, int out_size, void* d_ws, size_t ws_size,
                              hipStream_t stream) {
    const float* in_s  = (const float*)d_in[0];
    const float* in_v  = (const float*)d_in[1];
    const int*   snd   = (const int*)  d_in[2];
    const int*   rcv   = (const int*)  d_in[3];
    const float* e1_ws = (const float*)d_in[4];
    const float* e1_b  = (const float*)d_in[5];
    const float* e1_wv = (const float*)d_in[6];
    const float* e2_ws = (const float*)d_in[7];
    const float* e2_b  = (const float*)d_in[8];
    const float* e2_wv = (const float*)d_in[9];
    const float* n_ws  = (const float*)d_in[10];
    const float* n_b   = (const float*)d_in[11];
    const float* n_wv  = (const float*)d_in[12];
    const float* l_ws  = (const float*)d_in[13];
    const float* l_b   = (const float*)d_in[14];
    const float* l_wv  = (const float*)d_in[15];

    float* ws    = (float*)d_ws;
    float* cur_s = ws;                           // N*64   = 262144
    float* cur_v = cur_s + 262144;               // N*48   = 196608
    float* nxt_s = cur_v + 196608;               // N*64
    float* nxt_v = nxt_s + 262144;               // N*48
    float* y_s   = nxt_v + 196608;               // N*65   = 266240
    float* y_v   = y_s + 266240;                 // N*51   = 208896
    float* msg   = y_v + 208896;                 // E*116  = 3801088
    int*   deg    = (int*)(msg + 3801088);       // N
    int*   cursor = deg + 4096;                  // N
    int*   off    = cursor + 4096;               // N+1
    int*   elist  = off + 4097;                  // E

    hipMemsetAsync(deg, 0, (size_t)8192 * sizeof(int), stream);
    hipMemcpyAsync(cur_s, in_s, (size_t)262144 * sizeof(float), hipMemcpyDeviceToDevice, stream);
    hipMemcpyAsync(cur_v, in_v, (size_t)196608 * sizeof(float), hipMemcpyDeviceToDevice, stream);
    segnn_deg_kernel<<<EDG/256, 256, 0, stream>>>(rcv, deg);
    segnn_scan_kernel<<<1, 1024, 0, stream>>>(deg, off);
    segnn_scatter_kernel<<<EDG/256, 256, 0, stream>>>(rcv, off, cursor, elist);

    for (int step = 0; step < 3; ++step) {
        segnn_edge_fused<<<EDG/16, 256, 0, stream>>>(cur_s, cur_v, snd, rcv,
            e1_ws + (size_t)step*160*80, e1_b + step*80, e1_wv + (size_t)step*160*16,
            e2_ws + (size_t)(step*2+0)*80*80, e2_b + (step*2+0)*80, e2_wv + (size_t)(step*2+0)*80*16,
            e2_ws + (size_t)(step*2+1)*80*80, e2_b + (step*2+1)*80, e2_wv + (size_t)(step*2+1)*80*16,
            msg);
        segnn_gather_kernel<<<NND, 128, 0, stream>>>(msg, off, elist, y_s, y_v);

        segnn_node_kernel<<<NND/8, 512, 0, stream>>>(cur_s, cur_v, y_s, y_v,
            n_ws + (size_t)(step*3+0)*4432*80, n_b + (step*3+0)*80, n_wv + (size_t)(step*3+0)*2128*16,
            nxt_s, nxt_v);
        segnn_node_kernel<<<NND/8, 512, 0, stream>>>(nxt_s, nxt_v, y_s, y_v,
            n_ws + (size_t)(step*3+1)*4432*80, n_b + (step*3+1)*80, n_wv + (size_t)(step*3+1)*2128*16,
            cur_s, cur_v);
        segnn_node_kernel<<<NND/8, 512, 0, stream>>>(cur_s, cur_v, y_s, y_v,
            n_ws + (size_t)(step*3+2)*4432*80, n_b + (step*3+2)*80, n_wv + (size_t)(step*3+2)*2128*16,
            nxt_s, nxt_v);

        segnn_linear_kernel<<<(NND*112 + 255)/256, 256, 0, stream>>>(nxt_s, nxt_v,
            l_ws + (size_t)step*64*64, l_b + step*64, l_wv + (size_t)step*16*16,
            cur_s, cur_v, (step == 2) ? (float*)d_out : nullptr);
    }
}